// Round 1
// baseline (1502.812 us; speedup 1.0000x reference)
//
#include <hip/hip_runtime.h>

// Problem constants (reference: T=64 time steps, B=SEQ=128 batch, IN=256, H=512)
#define TT 64
#define BB 128
#define IND 256
#define HH 512
#define GG 2048      // 4*H
#define NCC 10
#define KFLAT 65536  // SEQ*H
#define HP2 520      // bf16 LDS row stride (512 + 8)
#define SP 36        // GEMM LDS short stride

typedef __attribute__((ext_vector_type(8))) short bf16x8;
typedef __attribute__((ext_vector_type(4))) float floatx4;

__device__ __forceinline__ unsigned short f2bf(float x) {   // RNE round to bf16
    unsigned u = __builtin_bit_cast(unsigned, x);
    u += 0x7fffu + ((u >> 16) & 1u);
    return (unsigned short)(u >> 16);
}
__device__ __forceinline__ float bf2f(unsigned short h) {
    unsigned u = ((unsigned)h) << 16;
    return __builtin_bit_cast(float, u);
}
__device__ __forceinline__ float pk2f(unsigned u) {
    float hi = __builtin_bit_cast(float, u & 0xffff0000u);
    float lo = __builtin_bit_cast(float, u << 16);
    return hi + lo;
}

// ---------------------------------------------------------------------------
// Elementwise: fp32 -> packed split-bf16 (hi<<16 | lo)
// ---------------------------------------------------------------------------
__global__ __launch_bounds__(256) void pack_split_kernel(
    const float* __restrict__ src, unsigned* __restrict__ dst, int n)
{
    for (int i = blockIdx.x * 256 + threadIdx.x; i < n; i += gridDim.x * 256) {
        float f = src[i];
        unsigned short hb = f2bf(f);
        unsigned short lb = f2bf(f - bf2f(hb));
        dst[i] = ((unsigned)hb << 16) | lb;
    }
}

// ---------------------------------------------------------------------------
// MFMA GEMM on packed split-bf16 (proven R6): layer-0 input transform only.
// ---------------------------------------------------------------------------
__global__ __launch_bounds__(256) void gemm_pk_mfma(
    const unsigned* __restrict__ A, const unsigned* __restrict__ W,
    const float* __restrict__ b0, const float* __restrict__ b1,
    float* __restrict__ C, int K, int N)
{
    __shared__ short Ahi[128][SP], Alo[128][SP], Whi[128][SP], Wlo[128][SP];

    const int tid  = threadIdx.x;
    const int lane = tid & 63;
    const int wv   = tid >> 6;
    const int wm   = (wv & 1) * 64;
    const int wn   = (wv >> 1) * 64;
    const int l15  = lane & 15;
    const int quad = lane >> 4;
    const int m0   = blockIdx.x * 128;
    const int n0   = blockIdx.y * 128;

    floatx4 acc[4][4];
    #pragma unroll
    for (int i = 0; i < 4; ++i)
        #pragma unroll
        for (int j = 0; j < 4; ++j)
            acc[i][j] = (floatx4){0.f, 0.f, 0.f, 0.f};

    for (int kc = 0; kc < K; kc += 32) {
        #pragma unroll
        for (int it = 0; it < 4; ++it) {
            const int lin = it * 256 + tid;
            const int row = lin >> 3;
            const int c4  = (lin & 7) * 4;
            uint4 va = *(const uint4*)&A[(size_t)(m0 + row) * K + kc + c4];
            uint2 ah, al;
            ah.x = (va.x >> 16) | (va.y & 0xffff0000u);
            ah.y = (va.z >> 16) | (va.w & 0xffff0000u);
            al.x = (va.x & 0xffffu) | (va.y << 16);
            al.y = (va.z & 0xffffu) | (va.w << 16);
            *(uint2*)&Ahi[row][c4] = ah;
            *(uint2*)&Alo[row][c4] = al;
            uint4 vw = *(const uint4*)&W[(size_t)(n0 + row) * K + kc + c4];
            uint2 wh, wl;
            wh.x = (vw.x >> 16) | (vw.y & 0xffff0000u);
            wh.y = (vw.z >> 16) | (vw.w & 0xffff0000u);
            wl.x = (vw.x & 0xffffu) | (vw.y << 16);
            wl.y = (vw.z & 0xffffu) | (vw.w << 16);
            *(uint2*)&Whi[row][c4] = wh;
            *(uint2*)&Wlo[row][c4] = wl;
        }
        __syncthreads();

        bf16x8 afh[4], afl[4], bfh[4], bfl[4];
        #pragma unroll
        for (int i = 0; i < 4; ++i) {
            afh[i] = *(const bf16x8*)&Ahi[wm + i * 16 + l15][quad * 8];
            afl[i] = *(const bf16x8*)&Alo[wm + i * 16 + l15][quad * 8];
            bfh[i] = *(const bf16x8*)&Whi[wn + i * 16 + l15][quad * 8];
            bfl[i] = *(const bf16x8*)&Wlo[wn + i * 16 + l15][quad * 8];
        }
        #pragma unroll
        for (int i = 0; i < 4; ++i)
            #pragma unroll
            for (int j = 0; j < 4; ++j) {
                acc[i][j] = __builtin_amdgcn_mfma_f32_16x16x32_bf16(afh[i], bfh[j], acc[i][j], 0, 0, 0);
                acc[i][j] = __builtin_amdgcn_mfma_f32_16x16x32_bf16(afh[i], bfl[j], acc[i][j], 0, 0, 0);
                acc[i][j] = __builtin_amdgcn_mfma_f32_16x16x32_bf16(afl[i], bfh[j], acc[i][j], 0, 0, 0);
            }
        __syncthreads();
    }

    #pragma unroll
    for (int i = 0; i < 4; ++i) {
        #pragma unroll
        for (int j = 0; j < 4; ++j) {
            const int n = n0 + wn + j * 16 + l15;
            const float bias = b0[n] + b1[n];
            #pragma unroll
            for (int r = 0; r < 4; ++r) {
                const int m = m0 + wm + i * 16 + quad * 4 + r;
                C[(size_t)m * N + n] = acc[i][j][r] + bias;
            }
        }
    }
}

// ---------------------------------------------------------------------------
// Stage 8 packed h-cells into LDS hi/lo planes. Plain wide loads — only
// called AFTER the flag handshake + acquire fence guarantees freshness.
// ---------------------------------------------------------------------------
__device__ __forceinline__ void stage8p(
    const unsigned* __restrict__ src, int bb, int kk,
    short (*Hs_hi)[HP2], short (*Hs_lo)[HP2])
{
    const uint4 v0 = *(const uint4*)(src);
    const uint4 v1 = *(const uint4*)(src + 4);
    uint4 hiv, lov;
    hiv.x = (v0.x >> 16) | (v0.y & 0xffff0000u);
    hiv.y = (v0.z >> 16) | (v0.w & 0xffff0000u);
    hiv.z = (v1.x >> 16) | (v1.y & 0xffff0000u);
    hiv.w = (v1.z >> 16) | (v1.w & 0xffff0000u);
    lov.x = (v0.x & 0xffffu) | (v0.y << 16);
    lov.y = (v0.z & 0xffffu) | (v0.w << 16);
    lov.z = (v1.x & 0xffffu) | (v1.y << 16);
    lov.w = (v1.z & 0xffffu) | (v1.w << 16);
    *(uint4*)&Hs_hi[bb][kk] = hiv;
    *(uint4*)&Hs_lo[bb][kk] = lov;
}

// System-scope relaxed poll: bypasses the (possibly stale) per-XCD L2 so
// readiness is detected at coherence-point latency, not L2-eviction latency.
__device__ __forceinline__ void spin_flag(const unsigned* p) {
    while (__hip_atomic_load(p, __ATOMIC_RELAXED, __HIP_MEMORY_SCOPE_SYSTEM) == 0u) { }
}

// ---------------------------------------------------------------------------
// FUSED two-layer persistent LSTM, release/acquire flag-synchronized
// pipeline. Blocks 0..127 = layer 0; blocks 128..255 = layer 1 (runs ~1
// step behind, self-timed). WG (bt, j0): batches [bt*32,+32) x 16 hidden
// units x 4 gates (wave g = gate g). Layer-1 WGs compute BOTH matmuls per
// step, weights in registers. Handshake: producer (bt, jsl) stores its h
// slice (relaxed-agent atomics, write-through), __syncthreads drains all
// lanes' vmcnt, then tid0 RELEASE-stores flag[layer][t+1][bt][jsl]
// (system scope -> L2 writeback + coherent store). Consumers spin on the
// 32 producer flags with system-scope relaxed loads (L2-bypassing),
// acquire-fence (invalidates L1/L2), then bulk-stage the tile with plain
// cacheable uint4 loads (clique members on the same XCD share refills).
// ---------------------------------------------------------------------------
__global__ __launch_bounds__(256, 1) void lstm_fused(
    const float* __restrict__ xg,     // [T][B][4H] layer-0 (biases included)
    const float* __restrict__ w_hh0,  // [4H][H] fp32
    const float* __restrict__ w_ih1,  // [4H][H] fp32
    const float* __restrict__ w_hh1,  // [4H][H] fp32
    const float* __restrict__ b_ih1, const float* __restrict__ b_hh1,
    unsigned* __restrict__ hpack0,    // [T+1][B][H] packed hi|lo, block 0 zeroed
    unsigned* __restrict__ hpack1,    // [T+1][B][H] packed hi|lo, block 0 zeroed
    unsigned* __restrict__ flags)     // [2][T+1][4][32] step-completion flags (zeroed)
{
    __shared__ short Ra_hi[32][HP2], Ra_lo[32][HP2];   // recurrent h tile
    __shared__ short Xa_hi[32][HP2], Xa_lo[32][HP2];   // layer-1 input h0 tile
    __shared__ float Gs[64][33];

    const int tid  = threadIdx.x;
    const int lane = tid & 63;
    const int wv   = tid >> 6;               // wave = gate 0..3
    const bool isB = blockIdx.x >= 128;
    const int blk  = blockIdx.x & 127;
    const int bt   = blk & 3;
    const int jsl  = blk >> 2;               // producer j-slice id 0..31
    const int j0   = jsl * 16;               // 16-unit slice
    const int l15  = lane & 15;
    const int quad = lane >> 4;

    // ---- preload recurrent-weight frags (16 rows: gate wv, units j0+l15) ----
    bf16x8 wa_hi[16], wa_lo[16], wx_hi[16], wx_lo[16];
    {
        const float* wsrc = isB ? w_hh1 : w_hh0;
        const float* wrow = wsrc + (size_t)(wv * HH + j0 + l15) * HH + quad * 8;
        #pragma unroll
        for (int kc = 0; kc < 16; ++kc) {
            float f[8];
            *(float4*)&f[0] = *(const float4*)&wrow[kc * 32];
            *(float4*)&f[4] = *(const float4*)&wrow[kc * 32 + 4];
            bf16x8 vh, vl;
            #pragma unroll
            for (int j = 0; j < 8; ++j) {
                unsigned short hb = f2bf(f[j]);
                vh[j] = (short)hb;
                vl[j] = (short)f2bf(f[j] - bf2f(hb));
            }
            wa_hi[kc] = vh; wa_lo[kc] = vl;
        }
        if (isB) {
            const float* xrow = w_ih1 + (size_t)(wv * HH + j0 + l15) * HH + quad * 8;
            #pragma unroll
            for (int kc = 0; kc < 16; ++kc) {
                float f[8];
                *(float4*)&f[0] = *(const float4*)&xrow[kc * 32];
                *(float4*)&f[4] = *(const float4*)&xrow[kc * 32 + 4];
                bf16x8 vh, vl;
                #pragma unroll
                for (int j = 0; j < 8; ++j) {
                    unsigned short hb = f2bf(f[j]);
                    vh[j] = (short)hb;
                    vl[j] = (short)f2bf(f[j] - bf2f(hb));
                }
                wx_hi[kc] = vh; wx_lo[kc] = vl;
            }
        }
    }

    // update-phase roles: (j_u, bu) and (j_u, bu+16)
    const int j_u = tid & 15;
    const int bu  = tid >> 4;          // 0..15
    float bias_i = 0.f, bias_f = 0.f, bias_g = 0.f, bias_o = 0.f;
    if (isB) {
        bias_i = b_ih1[j0 + j_u]            + b_hh1[j0 + j_u];
        bias_f = b_ih1[HH + j0 + j_u]       + b_hh1[HH + j0 + j_u];
        bias_g = b_ih1[2 * HH + j0 + j_u]   + b_hh1[2 * HH + j0 + j_u];
        bias_o = b_ih1[3 * HH + j0 + j_u]   + b_hh1[3 * HH + j0 + j_u];
    }

    unsigned* hp_rec = isB ? hpack1 : hpack0;
    const int layerBase = isB ? 65 : 0;
    float c0 = 0.f, c1 = 0.f;

    for (int t = 0; t < TT; ++t) {
        const unsigned* rec_base = hp_rec + (size_t)t * (BB * HH) + (size_t)bt * 32 * HH;
        const unsigned* inp_base = hpack0 + (size_t)(t + 1) * (BB * HH) + (size_t)bt * 32 * HH;

        // layer-0: xg loads (overlap poll latency)
        float xgv[2][4];
        if (!isB) {
            #pragma unroll
            for (int ccell = 0; ccell < 2; ++ccell) {
                const int b = bu + ccell * 16;
                const float* base = xg + (size_t)t * (BB * GG)
                                  + (size_t)(bt * 32 + b) * GG + j0 + j_u;
                xgv[ccell][0] = base[0];
                xgv[ccell][1] = base[HH];
                xgv[ccell][2] = base[2 * HH];
                xgv[ccell][3] = base[3 * HH];
            }
        }

        // ---- flag handshake (skip own slice: our stores are self-visible) ----
        const unsigned* fR = flags + ((layerBase + t) * 4 + bt) * 32;
        const unsigned* fX = flags + ((t + 1) * 4 + bt) * 32;
        if (lane < 32) {
            if (t > 0 && lane != jsl) spin_flag(fR + lane);
        } else if (isB) {
            spin_flag(fX + (lane - 32));
        }
        __builtin_amdgcn_fence(__ATOMIC_ACQUIRE, "agent");

        // ---- bulk stage with plain cacheable loads ----
        #pragma unroll
        for (int p = 0; p < 8; ++p) {
            const int idx = p * 2048 + tid * 8;
            stage8p(rec_base + idx, idx >> 9, idx & 511, Ra_hi, Ra_lo);
        }
        if (isB) {
            #pragma unroll
            for (int p = 0; p < 8; ++p) {
                const int idx = p * 2048 + tid * 8;
                stage8p(inp_base + idx, idx >> 9, idx & 511, Xa_hi, Xa_lo);
            }
        }
        __syncthreads();

        // ---- MFMA: acc[half] = Wrec . h_rec (+ Wih1 . h0 for layer 1) ----
        floatx4 aR0 = {0.f,0.f,0.f,0.f}, aR1 = {0.f,0.f,0.f,0.f};
        floatx4 aX0 = {0.f,0.f,0.f,0.f}, aX1 = {0.f,0.f,0.f,0.f};
        #pragma unroll
        for (int kc = 0; kc < 16; ++kc) {
            const int off = kc * 32 + quad * 8;
            bf16x8 r0h = *(const bf16x8*)&Ra_hi[l15][off];
            bf16x8 r0l = *(const bf16x8*)&Ra_lo[l15][off];
            bf16x8 r1h = *(const bf16x8*)&Ra_hi[16 + l15][off];
            bf16x8 r1l = *(const bf16x8*)&Ra_lo[16 + l15][off];
            aR0 = __builtin_amdgcn_mfma_f32_16x16x32_bf16(wa_hi[kc], r0h, aR0, 0, 0, 0);
            aR1 = __builtin_amdgcn_mfma_f32_16x16x32_bf16(wa_hi[kc], r1h, aR1, 0, 0, 0);
            aR0 = __builtin_amdgcn_mfma_f32_16x16x32_bf16(wa_hi[kc], r0l, aR0, 0, 0, 0);
            aR1 = __builtin_amdgcn_mfma_f32_16x16x32_bf16(wa_hi[kc], r1l, aR1, 0, 0, 0);
            aR0 = __builtin_amdgcn_mfma_f32_16x16x32_bf16(wa_lo[kc], r0h, aR0, 0, 0, 0);
            aR1 = __builtin_amdgcn_mfma_f32_16x16x32_bf16(wa_lo[kc], r1h, aR1, 0, 0, 0);
            if (isB) {
                bf16x8 x0h = *(const bf16x8*)&Xa_hi[l15][off];
                bf16x8 x0l = *(const bf16x8*)&Xa_lo[l15][off];
                bf16x8 x1h = *(const bf16x8*)&Xa_hi[16 + l15][off];
                bf16x8 x1l = *(const bf16x8*)&Xa_lo[16 + l15][off];
                aX0 = __builtin_amdgcn_mfma_f32_16x16x32_bf16(wx_hi[kc], x0h, aX0, 0, 0, 0);
                aX1 = __builtin_amdgcn_mfma_f32_16x16x32_bf16(wx_hi[kc], x1h, aX1, 0, 0, 0);
                aX0 = __builtin_amdgcn_mfma_f32_16x16x32_bf16(wx_hi[kc], x0l, aX0, 0, 0, 0);
                aX1 = __builtin_amdgcn_mfma_f32_16x16x32_bf16(wx_hi[kc], x1l, aX1, 0, 0, 0);
                aX0 = __builtin_amdgcn_mfma_f32_16x16x32_bf16(wx_lo[kc], x0h, aX0, 0, 0, 0);
                aX1 = __builtin_amdgcn_mfma_f32_16x16x32_bf16(wx_lo[kc], x1h, aX1, 0, 0, 0);
            }
        }

        // ---- exchange preacts: rows = gate*16 + unit(quad*4+r) ----
        #pragma unroll
        for (int r = 0; r < 4; ++r) {
            Gs[wv * 16 + quad * 4 + r][l15]      = aR0[r] + aX0[r];
            Gs[wv * 16 + quad * 4 + r][16 + l15] = aR1[r] + aX1[r];
        }
        __syncthreads();

        // ---- elementwise update for 2 cells; packed split-bf16 store ----
        #pragma unroll
        for (int ccell = 0; ccell < 2; ++ccell) {
            const int b = bu + ccell * 16;
            float gi = Gs[j_u][b],      gf = Gs[16 + j_u][b];
            float gg = Gs[32 + j_u][b], go = Gs[48 + j_u][b];
            if (isB) { gi += bias_i; gf += bias_f; gg += bias_g; go += bias_o; }
            else     { gi += xgv[ccell][0]; gf += xgv[ccell][1];
                       gg += xgv[ccell][2]; go += xgv[ccell][3]; }
            const float si = 1.f / (1.f + __expf(-gi));
            const float sf = 1.f / (1.f + __expf(-gf));
            const float tg = 2.f / (1.f + __expf(-2.f * gg)) - 1.f;
            const float so = 1.f / (1.f + __expf(-go));
            float& cr = ccell ? c1 : c0;
            cr = sf * cr + si * tg;
            const float th = 2.f / (1.f + __expf(-2.f * cr)) - 1.f;
            const float hval = so * th;
            const unsigned short hb = f2bf(hval);
            const unsigned short lb = f2bf(hval - bf2f(hb));
            const unsigned pk = ((unsigned)hb << 16) | (unsigned)lb;
            __hip_atomic_store(
                &hp_rec[(size_t)(t + 1) * (BB * HH) + (size_t)(bt * 32 + b) * HH + j0 + j_u],
                pk, __ATOMIC_RELAXED, __HIP_MEMORY_SCOPE_AGENT);
        }
        __syncthreads();   // drains every lane's stores (vmcnt 0) before release

        // ---- publish: release-store completion flag for this slice ----
        if (tid == 0)
            __hip_atomic_store(
                flags + ((layerBase + (t + 1)) * 4 + bt) * 32 + jsl,
                1u, __ATOMIC_RELEASE, __HIP_MEMORY_SCOPE_SYSTEM);
    }
}

// ---------------------------------------------------------------------------
// Classifier split-K partial GEMM on packed h cells (full 16-bit lo now)
// ---------------------------------------------------------------------------
__global__ __launch_bounds__(256) void cls_partial_kernel(
    const unsigned* __restrict__ A, const float* __restrict__ W,
    float* __restrict__ part)
{
    const int n0 = blockIdx.x * 64;
    const int s  = blockIdx.y;
    const int kbase = s * 2048;
    const int tid = threadIdx.x;
    __shared__ float As[32][68];
    __shared__ float Bs[32][68];
    const int tm = tid >> 4, tn = tid & 15;
    float acc[4][4] = {};

    for (int kt = 0; kt < 2048; kt += 32) {
        #pragma unroll
        for (int q = tid; q < 512; q += 256) {
            const int mm = q >> 3;
            const int kq = q & 7;
            uint4 v = *(const uint4*)&A[(size_t)mm * KFLAT + kbase + kt + kq * 4];
            As[kq*4+0][mm] = pk2f(v.x); As[kq*4+1][mm] = pk2f(v.y);
            As[kq*4+2][mm] = pk2f(v.z); As[kq*4+3][mm] = pk2f(v.w);
            float4 w = *(const float4*)&W[(size_t)(n0 + mm) * KFLAT + kbase + kt + kq * 4];
            Bs[kq*4+0][mm] = w.x; Bs[kq*4+1][mm] = w.y;
            Bs[kq*4+2][mm] = w.z; Bs[kq*4+3][mm] = w.w;
        }
        __syncthreads();
        #pragma unroll
        for (int k = 0; k < 32; ++k) {
            float4 a = *(const float4*)&As[k][tm * 4];
            float4 b = *(const float4*)&Bs[k][tn * 4];
            acc[0][0] += a.x*b.x; acc[0][1] += a.x*b.y; acc[0][2] += a.x*b.z; acc[0][3] += a.x*b.w;
            acc[1][0] += a.y*b.x; acc[1][1] += a.y*b.y; acc[1][2] += a.y*b.z; acc[1][3] += a.y*b.w;
            acc[2][0] += a.z*b.x; acc[2][1] += a.z*b.y; acc[2][2] += a.z*b.z; acc[2][3] += a.z*b.w;
            acc[3][0] += a.w*b.x; acc[3][1] += a.w*b.y; acc[3][2] += a.w*b.z; acc[3][3] += a.w*b.w;
        }
        __syncthreads();
    }
    #pragma unroll
    for (int i = 0; i < 4; ++i) {
        const int m = tm * 4 + i;
        #pragma unroll
        for (int j = 0; j < 4; ++j) {
            part[((size_t)s * 64 + m) * 512 + n0 + tn * 4 + j] = acc[i][j];
        }
    }
}

// ---------------------------------------------------------------------------
// Classifier finish (unchanged)
// ---------------------------------------------------------------------------
__global__ __launch_bounds__(256) void cls_final_kernel(
    const float* __restrict__ part, const float* __restrict__ b1,
    const float* __restrict__ w2, const float* __restrict__ b2,
    float* __restrict__ out)
{
    const int t = blockIdx.x;
    __shared__ float hm[512];
    for (int n = threadIdx.x; n < 512; n += 256) {
        float sacc = b1[n];
        for (int sl = 0; sl < 32; ++sl)
            sacc += part[((size_t)sl * 64 + t) * 512 + n];
        hm[n] = fmaxf(sacc, 0.f);
    }
    __syncthreads();
    if (threadIdx.x < NCC) {
        float sacc = b2[threadIdx.x];
        const float* wr = w2 + (size_t)threadIdx.x * 512;
        for (int n = 0; n < 512; ++n) sacc += hm[n] * wr[n];
        out[t * NCC + threadIdx.x] = sacc;
    }
}

// ---------------------------------------------------------------------------
extern "C" void kernel_launch(void* const* d_in, const int* in_sizes, int n_in,
                              void* d_out, int out_size, void* d_ws, size_t ws_size,
                              hipStream_t stream)
{
    const float* x     = (const float*)d_in[0];
    const float* w_ih0 = (const float*)d_in[1];
    const float* w_hh0 = (const float*)d_in[2];
    const float* b_ih0 = (const float*)d_in[3];
    const float* b_hh0 = (const float*)d_in[4];
    const float* b_ih1 = (const float*)d_in[7];
    const float* w_ih1 = (const float*)d_in[5];
    const float* w_hh1 = (const float*)d_in[6];
    const float* b_hh1 = (const float*)d_in[8];
    const float* w1    = (const float*)d_in[9];
    const float* b1    = (const float*)d_in[10];
    const float* w2    = (const float*)d_in[11];
    const float* b2    = (const float*)d_in[12];
    float* out = (float*)d_out;

    // Workspace (~102.1 MB): hpack1 region is ALIASED over xpk/w0pk (dead
    // after the layer-0 GEMM). All t>=1 h reads are gated by flags (zeroed
    // each launch), so no scrub needed. flags alias the part region (part
    // is only written after lstm_fused completes).
    float*    ws     = (float*)d_ws;
    float*    xg     = ws;                                      // 64 MB
    unsigned* hpack0 = (unsigned*)(xg + (size_t)8192 * 2048);   // 17.04 MB
    unsigned* hpack1 = hpack0 + (size_t)65 * BB * HH;           // 17.04 MB (aliased)
    unsigned* xpk    = hpack1;                                  // 8 MB   (dies at GEMM)
    unsigned* w0pk   = xpk + (size_t)8192 * IND;                // 2 MB   (dies at GEMM)
    float*    part   = (float*)(hpack1 + (size_t)65 * BB * HH); // 4 MB
    unsigned* flags  = (unsigned*)part;                         // 66.6 KB (dies at cls)

    // ---- pack layer-0 GEMM inputs ----
    pack_split_kernel<<<1024, 256, 0, stream>>>(x, xpk, 8192 * IND);
    pack_split_kernel<<<512,  256, 0, stream>>>(w_ih0, w0pk, GG * IND);
    hipMemsetAsync(hpack0, 0, (size_t)BB * HH * sizeof(unsigned), stream);  // h0 t=0
    hipMemsetAsync(flags, 0, (size_t)2 * 65 * 4 * 32 * sizeof(unsigned), stream);

    // ---- layer-0 input transform ----
    gemm_pk_mfma<<<dim3(8192 / 128, GG / 128), 256, 0, stream>>>(
        xpk, w0pk, b_ih0, b_hh0, xg, IND, GG);

    // ---- zero t=0 block of hpack1 (after GEMM: aliased region now dead) ----
    hipMemsetAsync(hpack1, 0, (size_t)BB * HH * sizeof(unsigned), stream);

    // ---- fused two-layer recurrence ----
    lstm_fused<<<256, 256, 0, stream>>>(
        xg, w_hh0, w_ih1, w_hh1, b_ih1, b_hh1, hpack0, hpack1, flags);

    // ---- classifier (h1, blocks 1..64) ----
    cls_partial_kernel<<<dim3(512 / 64, 32), 256, 0, stream>>>(
        hpack1 + (size_t)BB * HH, w1, part);
    cls_final_kernel<<<64, 256, 0, stream>>>(part, b1, w2, b2, out);
}

// Round 2
// 987.834 us; speedup vs baseline: 1.5213x; 1.5213x over previous
//
#include <hip/hip_runtime.h>

// Problem constants (reference: T=64 time steps, B=SEQ=128 batch, IN=256, H=512)
#define TT 64
#define BB 128
#define IND 256
#define HH 512
#define GG 2048      // 4*H
#define NCC 10
#define KFLAT 65536  // SEQ*H
#define HP2 520      // bf16 LDS row stride (512 + 8)
#define SP 36        // GEMM LDS short stride

typedef __attribute__((ext_vector_type(8))) short bf16x8;
typedef __attribute__((ext_vector_type(4))) float floatx4;

__device__ __forceinline__ unsigned short f2bf(float x) {   // RNE round to bf16
    unsigned u = __builtin_bit_cast(unsigned, x);
    u += 0x7fffu + ((u >> 16) & 1u);
    return (unsigned short)(u >> 16);
}
__device__ __forceinline__ float bf2f(unsigned short h) {
    unsigned u = ((unsigned)h) << 16;
    return __builtin_bit_cast(float, u);
}
__device__ __forceinline__ float pk2f(unsigned u) {
    float hi = __builtin_bit_cast(float, u & 0xffff0000u);
    float lo = __builtin_bit_cast(float, u << 16);
    return hi + lo;
}

// ---------------------------------------------------------------------------
// Elementwise: fp32 -> packed split-bf16 (hi<<16 | lo)
// ---------------------------------------------------------------------------
__global__ __launch_bounds__(256) void pack_split_kernel(
    const float* __restrict__ src, unsigned* __restrict__ dst, int n)
{
    for (int i = blockIdx.x * 256 + threadIdx.x; i < n; i += gridDim.x * 256) {
        float f = src[i];
        unsigned short hb = f2bf(f);
        unsigned short lb = f2bf(f - bf2f(hb));
        dst[i] = ((unsigned)hb << 16) | lb;
    }
}

// ---------------------------------------------------------------------------
// MFMA GEMM on packed split-bf16 (proven R6): layer-0 input transform only.
// ---------------------------------------------------------------------------
__global__ __launch_bounds__(256) void gemm_pk_mfma(
    const unsigned* __restrict__ A, const unsigned* __restrict__ W,
    const float* __restrict__ b0, const float* __restrict__ b1,
    float* __restrict__ C, int K, int N)
{
    __shared__ short Ahi[128][SP], Alo[128][SP], Whi[128][SP], Wlo[128][SP];

    const int tid  = threadIdx.x;
    const int lane = tid & 63;
    const int wv   = tid >> 6;
    const int wm   = (wv & 1) * 64;
    const int wn   = (wv >> 1) * 64;
    const int l15  = lane & 15;
    const int quad = lane >> 4;
    const int m0   = blockIdx.x * 128;
    const int n0   = blockIdx.y * 128;

    floatx4 acc[4][4];
    #pragma unroll
    for (int i = 0; i < 4; ++i)
        #pragma unroll
        for (int j = 0; j < 4; ++j)
            acc[i][j] = (floatx4){0.f, 0.f, 0.f, 0.f};

    for (int kc = 0; kc < K; kc += 32) {
        #pragma unroll
        for (int it = 0; it < 4; ++it) {
            const int lin = it * 256 + tid;
            const int row = lin >> 3;
            const int c4  = (lin & 7) * 4;
            uint4 va = *(const uint4*)&A[(size_t)(m0 + row) * K + kc + c4];
            uint2 ah, al;
            ah.x = (va.x >> 16) | (va.y & 0xffff0000u);
            ah.y = (va.z >> 16) | (va.w & 0xffff0000u);
            al.x = (va.x & 0xffffu) | (va.y << 16);
            al.y = (va.z & 0xffffu) | (va.w << 16);
            *(uint2*)&Ahi[row][c4] = ah;
            *(uint2*)&Alo[row][c4] = al;
            uint4 vw = *(const uint4*)&W[(size_t)(n0 + row) * K + kc + c4];
            uint2 wh, wl;
            wh.x = (vw.x >> 16) | (vw.y & 0xffff0000u);
            wh.y = (vw.z >> 16) | (vw.w & 0xffff0000u);
            wl.x = (vw.x & 0xffffu) | (vw.y << 16);
            wl.y = (vw.z & 0xffffu) | (vw.w << 16);
            *(uint2*)&Whi[row][c4] = wh;
            *(uint2*)&Wlo[row][c4] = wl;
        }
        __syncthreads();

        bf16x8 afh[4], afl[4], bfh[4], bfl[4];
        #pragma unroll
        for (int i = 0; i < 4; ++i) {
            afh[i] = *(const bf16x8*)&Ahi[wm + i * 16 + l15][quad * 8];
            afl[i] = *(const bf16x8*)&Alo[wm + i * 16 + l15][quad * 8];
            bfh[i] = *(const bf16x8*)&Whi[wn + i * 16 + l15][quad * 8];
            bfl[i] = *(const bf16x8*)&Wlo[wn + i * 16 + l15][quad * 8];
        }
        #pragma unroll
        for (int i = 0; i < 4; ++i)
            #pragma unroll
            for (int j = 0; j < 4; ++j) {
                acc[i][j] = __builtin_amdgcn_mfma_f32_16x16x32_bf16(afh[i], bfh[j], acc[i][j], 0, 0, 0);
                acc[i][j] = __builtin_amdgcn_mfma_f32_16x16x32_bf16(afh[i], bfl[j], acc[i][j], 0, 0, 0);
                acc[i][j] = __builtin_amdgcn_mfma_f32_16x16x32_bf16(afl[i], bfh[j], acc[i][j], 0, 0, 0);
            }
        __syncthreads();
    }

    #pragma unroll
    for (int i = 0; i < 4; ++i) {
        #pragma unroll
        for (int j = 0; j < 4; ++j) {
            const int n = n0 + wn + j * 16 + l15;
            const float bias = b0[n] + b1[n];
            #pragma unroll
            for (int r = 0; r < 4; ++r) {
                const int m = m0 + wm + i * 16 + quad * 4 + r;
                C[(size_t)m * N + n] = acc[i][j][r] + bias;
            }
        }
    }
}

// ---------------------------------------------------------------------------
// Stage 8 tagged h-cells into LDS hi/lo planes — ATOMIC (L2-bypassing) path.
// Used only as the retry fallback; returns nonzero on tag miss.
// ---------------------------------------------------------------------------
__device__ __forceinline__ unsigned stage8_atomic(
    const unsigned long long* __restrict__ src, int bb, int kk, unsigned exp,
    short (*Hs_hi)[HP2], short (*Hs_lo)[HP2])
{
    unsigned long long q0 = __hip_atomic_load(src + 0, __ATOMIC_RELAXED, __HIP_MEMORY_SCOPE_AGENT);
    unsigned long long q1 = __hip_atomic_load(src + 1, __ATOMIC_RELAXED, __HIP_MEMORY_SCOPE_AGENT);
    unsigned long long q2 = __hip_atomic_load(src + 2, __ATOMIC_RELAXED, __HIP_MEMORY_SCOPE_AGENT);
    unsigned long long q3 = __hip_atomic_load(src + 3, __ATOMIC_RELAXED, __HIP_MEMORY_SCOPE_AGENT);
    unsigned c0 = (unsigned)q0, c1 = (unsigned)(q0 >> 32);
    unsigned c2 = (unsigned)q1, c3 = (unsigned)(q1 >> 32);
    unsigned c4 = (unsigned)q2, c5 = (unsigned)(q2 >> 32);
    unsigned c6 = (unsigned)q3, c7 = (unsigned)(q3 >> 32);
    unsigned bad = ((c0 ^ exp) | (c1 ^ exp) | (c2 ^ exp) | (c3 ^ exp)
                  | (c4 ^ exp) | (c5 ^ exp) | (c6 ^ exp) | (c7 ^ exp)) & 0xFu;
    uint4 hiv, lov;
    hiv.x = (c0 >> 16) | (c1 & 0xffff0000u);
    hiv.y = (c2 >> 16) | (c3 & 0xffff0000u);
    hiv.z = (c4 >> 16) | (c5 & 0xffff0000u);
    hiv.w = (c6 >> 16) | (c7 & 0xffff0000u);
    lov.x = (c0 & 0xFFF0u) | ((c1 & 0xFFF0u) << 16);
    lov.y = (c2 & 0xFFF0u) | ((c3 & 0xFFF0u) << 16);
    lov.z = (c4 & 0xFFF0u) | ((c5 & 0xFFF0u) << 16);
    lov.w = (c6 & 0xFFF0u) | ((c7 & 0xFFF0u) << 16);
    *(uint4*)&Hs_hi[bb][kk] = hiv;
    *(uint4*)&Hs_lo[bb][kk] = lov;
    return bad;
}

// ---------------------------------------------------------------------------
// Stage 8 tagged h-cells — PLAIN CACHED path (fast). Only issued after the
// flag handshake says the producer's stores have landed at the coherence
// point; the address is fresh (never touched pre-flag in this dispatch),
// so the L2 fill gets current data and same-XCD clique members share it.
// Tag check retained: any mismatch falls back to stage8_atomic.
// ---------------------------------------------------------------------------
__device__ __forceinline__ unsigned stage8_plain(
    const unsigned* __restrict__ src, int bb, int kk, unsigned exp,
    short (*Hs_hi)[HP2], short (*Hs_lo)[HP2])
{
    const uint4 v0 = *(const uint4*)(src);
    const uint4 v1 = *(const uint4*)(src + 4);
    unsigned bad = ((v0.x ^ exp) | (v0.y ^ exp) | (v0.z ^ exp) | (v0.w ^ exp)
                  | (v1.x ^ exp) | (v1.y ^ exp) | (v1.z ^ exp) | (v1.w ^ exp)) & 0xFu;
    uint4 hiv, lov;
    hiv.x = (v0.x >> 16) | (v0.y & 0xffff0000u);
    hiv.y = (v0.z >> 16) | (v0.w & 0xffff0000u);
    hiv.z = (v1.x >> 16) | (v1.y & 0xffff0000u);
    hiv.w = (v1.z >> 16) | (v1.w & 0xffff0000u);
    lov.x = (v0.x & 0xFFF0u) | ((v0.y & 0xFFF0u) << 16);
    lov.y = (v0.z & 0xFFF0u) | ((v0.w & 0xFFF0u) << 16);
    lov.z = (v1.x & 0xFFF0u) | ((v1.y & 0xFFF0u) << 16);
    lov.w = (v1.z & 0xFFF0u) | ((v1.w & 0xFFF0u) << 16);
    *(uint4*)&Hs_hi[bb][kk] = hiv;
    *(uint4*)&Hs_lo[bb][kk] = lov;
    return bad;
}

// Agent-scope relaxed poll: L2-bypassing load observes the coherence point
// directly. No fences — visibility ordering comes from the producer's
// barrier-drained stores preceding the flag store.
__device__ __forceinline__ void spin_flag(const unsigned* p) {
    while (__hip_atomic_load(p, __ATOMIC_RELAXED, __HIP_MEMORY_SCOPE_AGENT) == 0u) { }
}

// ---------------------------------------------------------------------------
// FUSED two-layer persistent LSTM. Blocks 0..127 = layer 0; blocks
// 128..255 = layer 1 (runs ~1 step behind, self-timed). WG (bt, j0):
// batches [bt*32,+32) x 16 hidden units x 4 gates (wave g = gate g).
// Layer-1 WGs compute BOTH matmuls per step, weights in registers.
//
// Sync protocol (no fences): producer stores its tagged h slice with
// relaxed-agent atomics (L2-bypass -> coherence point), __syncthreads
// drains vmcnt, then tid0 stores flag[layer][t+1][bt][jsl] (relaxed
// agent). Consumers spin on the 32 producer flags (agent atomics), then
// bulk-stage with plain cacheable uint4 loads — same-XCD clique members
// share the L2 fill. Tags (lo nibble, gen%9) are kept as the correctness
// net: any stale/mismatched cell group retries via L2-bypassing atomic
// loads (guaranteed progress). 0xA (harness poison) never matches a tag.
// ---------------------------------------------------------------------------
__global__ __launch_bounds__(256, 1) void lstm_fused(
    const float* __restrict__ xg,     // [T][B][4H] layer-0 (biases included)
    const float* __restrict__ w_hh0,  // [4H][H] fp32
    const float* __restrict__ w_ih1,  // [4H][H] fp32
    const float* __restrict__ w_hh1,  // [4H][H] fp32
    const float* __restrict__ b_ih1, const float* __restrict__ b_hh1,
    unsigned* __restrict__ hpack0,    // [T+1][B][H] tagged, block 0 zeroed
    unsigned* __restrict__ hpack1,    // [T+1][B][H] tagged, block 0 zeroed
    unsigned* __restrict__ flags)     // [2][T+1][4][32] step flags (zeroed)
{
    __shared__ short Ra_hi[32][HP2], Ra_lo[32][HP2];   // recurrent h tile
    __shared__ short Xa_hi[32][HP2], Xa_lo[32][HP2];   // layer-1 input h0 tile
    __shared__ float Gs[64][33];

    const int tid  = threadIdx.x;
    const int lane = tid & 63;
    const int wv   = tid >> 6;               // wave = gate 0..3
    const bool isB = blockIdx.x >= 128;
    const int blk  = blockIdx.x & 127;
    const int bt   = blk & 3;
    const int jsl  = blk >> 2;               // producer j-slice id 0..31
    const int j0   = jsl * 16;               // 16-unit slice
    const int l15  = lane & 15;
    const int quad = lane >> 4;

    // ---- preload recurrent-weight frags (16 rows: gate wv, units j0+l15) ----
    bf16x8 wa_hi[16], wa_lo[16], wx_hi[16], wx_lo[16];
    {
        const float* wsrc = isB ? w_hh1 : w_hh0;
        const float* wrow = wsrc + (size_t)(wv * HH + j0 + l15) * HH + quad * 8;
        #pragma unroll
        for (int kc = 0; kc < 16; ++kc) {
            float f[8];
            *(float4*)&f[0] = *(const float4*)&wrow[kc * 32];
            *(float4*)&f[4] = *(const float4*)&wrow[kc * 32 + 4];
            bf16x8 vh, vl;
            #pragma unroll
            for (int j = 0; j < 8; ++j) {
                unsigned short hb = f2bf(f[j]);
                vh[j] = (short)hb;
                vl[j] = (short)f2bf(f[j] - bf2f(hb));
            }
            wa_hi[kc] = vh; wa_lo[kc] = vl;
        }
        if (isB) {
            const float* xrow = w_ih1 + (size_t)(wv * HH + j0 + l15) * HH + quad * 8;
            #pragma unroll
            for (int kc = 0; kc < 16; ++kc) {
                float f[8];
                *(float4*)&f[0] = *(const float4*)&xrow[kc * 32];
                *(float4*)&f[4] = *(const float4*)&xrow[kc * 32 + 4];
                bf16x8 vh, vl;
                #pragma unroll
                for (int j = 0; j < 8; ++j) {
                    unsigned short hb = f2bf(f[j]);
                    vh[j] = (short)hb;
                    vl[j] = (short)f2bf(f[j] - bf2f(hb));
                }
                wx_hi[kc] = vh; wx_lo[kc] = vl;
            }
        }
    }

    // update-phase roles: (j_u, bu) and (j_u, bu+16)
    const int j_u = tid & 15;
    const int bu  = tid >> 4;          // 0..15
    float bias_i = 0.f, bias_f = 0.f, bias_g = 0.f, bias_o = 0.f;
    if (isB) {
        bias_i = b_ih1[j0 + j_u]            + b_hh1[j0 + j_u];
        bias_f = b_ih1[HH + j0 + j_u]       + b_hh1[HH + j0 + j_u];
        bias_g = b_ih1[2 * HH + j0 + j_u]   + b_hh1[2 * HH + j0 + j_u];
        bias_o = b_ih1[3 * HH + j0 + j_u]   + b_hh1[3 * HH + j0 + j_u];
    }

    unsigned* hp_rec = isB ? hpack1 : hpack0;
    const int layerBase = isB ? 65 : 0;
    float c0 = 0.f, c1 = 0.f;

    for (int t = 0; t < TT; ++t) {
        const unsigned* rec_base = hp_rec + (size_t)t * (BB * HH) + (size_t)bt * 32 * HH;
        const unsigned* inp_base = hpack0 + (size_t)(t + 1) * (BB * HH) + (size_t)bt * 32 * HH;
        const unsigned expR = (unsigned)t % 9u;
        const unsigned expX = (unsigned)(t + 1) % 9u;

        // layer-0: xg loads (overlap poll latency)
        float xgv[2][4];
        if (!isB) {
            #pragma unroll
            for (int ccell = 0; ccell < 2; ++ccell) {
                const int b = bu + ccell * 16;
                const float* base = xg + (size_t)t * (BB * GG)
                                  + (size_t)(bt * 32 + b) * GG + j0 + j_u;
                xgv[ccell][0] = base[0];
                xgv[ccell][1] = base[HH];
                xgv[ccell][2] = base[2 * HH];
                xgv[ccell][3] = base[3 * HH];
            }
        }

        // ---- flag handshake (own slice skipped: own stores are drained) ----
        const unsigned* fR = flags + ((layerBase + t) * 4 + bt) * 32;
        const unsigned* fX = flags + ((t + 1) * 4 + bt) * 32;
        if (lane < 32) {
            if (t > 0 && lane != jsl) spin_flag(fR + lane);
        } else if (isB) {
            spin_flag(fX + (lane - 32));
        }
        asm volatile("" ::: "memory");   // no staging loads hoisted above spin

        // ---- bulk stage: plain cached loads, tag-checked ----
        unsigned missR = 0, missX = 0;
        #pragma unroll
        for (int p = 0; p < 8; ++p) {
            const int idx = p * 2048 + tid * 8;
            unsigned bad = stage8_plain(rec_base + idx, idx >> 9, idx & 511,
                                        expR, Ra_hi, Ra_lo);
            missR |= (bad ? 1u : 0u) << p;
        }
        if (isB) {
            #pragma unroll
            for (int p = 0; p < 8; ++p) {
                const int idx = p * 2048 + tid * 8;
                unsigned bad = stage8_plain(inp_base + idx, idx >> 9, idx & 511,
                                            expX, Xa_hi, Xa_lo);
                missX |= (bad ? 1u : 0u) << p;
            }
        }
        // fallback: L2-bypassing atomic retries (should ~never trigger)
        while (missR | missX) {
            #pragma unroll
            for (int p = 0; p < 8; ++p) {
                if (missR & (1u << p)) {
                    const int idx = p * 2048 + tid * 8;
                    if (!stage8_atomic((const unsigned long long*)(rec_base + idx),
                                       idx >> 9, idx & 511, expR, Ra_hi, Ra_lo))
                        missR &= ~(1u << p);
                }
                if (missX & (1u << p)) {
                    const int idx = p * 2048 + tid * 8;
                    if (!stage8_atomic((const unsigned long long*)(inp_base + idx),
                                       idx >> 9, idx & 511, expX, Xa_hi, Xa_lo))
                        missX &= ~(1u << p);
                }
            }
        }
        __syncthreads();

        // ---- MFMA: acc[half] = Wrec . h_rec (+ Wih1 . h0 for layer 1) ----
        floatx4 aR0 = {0.f,0.f,0.f,0.f}, aR1 = {0.f,0.f,0.f,0.f};
        floatx4 aX0 = {0.f,0.f,0.f,0.f}, aX1 = {0.f,0.f,0.f,0.f};
        #pragma unroll
        for (int kc = 0; kc < 16; ++kc) {
            const int off = kc * 32 + quad * 8;
            bf16x8 r0h = *(const bf16x8*)&Ra_hi[l15][off];
            bf16x8 r0l = *(const bf16x8*)&Ra_lo[l15][off];
            bf16x8 r1h = *(const bf16x8*)&Ra_hi[16 + l15][off];
            bf16x8 r1l = *(const bf16x8*)&Ra_lo[16 + l15][off];
            aR0 = __builtin_amdgcn_mfma_f32_16x16x32_bf16(wa_hi[kc], r0h, aR0, 0, 0, 0);
            aR1 = __builtin_amdgcn_mfma_f32_16x16x32_bf16(wa_hi[kc], r1h, aR1, 0, 0, 0);
            aR0 = __builtin_amdgcn_mfma_f32_16x16x32_bf16(wa_hi[kc], r0l, aR0, 0, 0, 0);
            aR1 = __builtin_amdgcn_mfma_f32_16x16x32_bf16(wa_hi[kc], r1l, aR1, 0, 0, 0);
            aR0 = __builtin_amdgcn_mfma_f32_16x16x32_bf16(wa_lo[kc], r0h, aR0, 0, 0, 0);
            aR1 = __builtin_amdgcn_mfma_f32_16x16x32_bf16(wa_lo[kc], r1h, aR1, 0, 0, 0);
            if (isB) {
                bf16x8 x0h = *(const bf16x8*)&Xa_hi[l15][off];
                bf16x8 x0l = *(const bf16x8*)&Xa_lo[l15][off];
                bf16x8 x1h = *(const bf16x8*)&Xa_hi[16 + l15][off];
                bf16x8 x1l = *(const bf16x8*)&Xa_lo[16 + l15][off];
                aX0 = __builtin_amdgcn_mfma_f32_16x16x32_bf16(wx_hi[kc], x0h, aX0, 0, 0, 0);
                aX1 = __builtin_amdgcn_mfma_f32_16x16x32_bf16(wx_hi[kc], x1h, aX1, 0, 0, 0);
                aX0 = __builtin_amdgcn_mfma_f32_16x16x32_bf16(wx_hi[kc], x0l, aX0, 0, 0, 0);
                aX1 = __builtin_amdgcn_mfma_f32_16x16x32_bf16(wx_hi[kc], x1l, aX1, 0, 0, 0);
                aX0 = __builtin_amdgcn_mfma_f32_16x16x32_bf16(wx_lo[kc], x0h, aX0, 0, 0, 0);
                aX1 = __builtin_amdgcn_mfma_f32_16x16x32_bf16(wx_lo[kc], x1h, aX1, 0, 0, 0);
            }
        }

        // ---- exchange preacts: rows = gate*16 + unit(quad*4+r) ----
        #pragma unroll
        for (int r = 0; r < 4; ++r) {
            Gs[wv * 16 + quad * 4 + r][l15]      = aR0[r] + aX0[r];
            Gs[wv * 16 + quad * 4 + r][16 + l15] = aR1[r] + aX1[r];
        }
        __syncthreads();

        // ---- elementwise update for 2 cells; tagged fire-and-forget store ----
        const unsigned tag = (unsigned)(t + 1) % 9u;
        #pragma unroll
        for (int ccell = 0; ccell < 2; ++ccell) {
            const int b = bu + ccell * 16;
            float gi = Gs[j_u][b],      gf = Gs[16 + j_u][b];
            float gg = Gs[32 + j_u][b], go = Gs[48 + j_u][b];
            if (isB) { gi += bias_i; gf += bias_f; gg += bias_g; go += bias_o; }
            else     { gi += xgv[ccell][0]; gf += xgv[ccell][1];
                       gg += xgv[ccell][2]; go += xgv[ccell][3]; }
            const float si = 1.f / (1.f + __expf(-gi));
            const float sf = 1.f / (1.f + __expf(-gf));
            const float tg = 2.f / (1.f + __expf(-2.f * gg)) - 1.f;
            const float so = 1.f / (1.f + __expf(-go));
            float& cr = ccell ? c1 : c0;
            cr = sf * cr + si * tg;
            const float th = 2.f / (1.f + __expf(-2.f * cr)) - 1.f;
            const float hval = so * th;
            const unsigned short hb = f2bf(hval);
            const unsigned short lb = f2bf(hval - bf2f(hb));
            const unsigned pk = ((unsigned)hb << 16) | ((unsigned)lb & 0xFFF0u) | tag;
            __hip_atomic_store(
                &hp_rec[(size_t)(t + 1) * (BB * HH) + (size_t)(bt * 32 + b) * HH + j0 + j_u],
                pk, __ATOMIC_RELAXED, __HIP_MEMORY_SCOPE_AGENT);
        }
        __syncthreads();   // drains every lane's h stores (vmcnt 0)

        // ---- publish: flag store for this slice (after the drain) ----
        if (tid == 0)
            __hip_atomic_store(
                flags + ((layerBase + (t + 1)) * 4 + bt) * 32 + jsl,
                1u, __ATOMIC_RELAXED, __HIP_MEMORY_SCOPE_AGENT);
    }
}

// ---------------------------------------------------------------------------
// Classifier split-K partial GEMM on tagged h cells (mask tag nibble)
// ---------------------------------------------------------------------------
__global__ __launch_bounds__(256) void cls_partial_kernel(
    const unsigned* __restrict__ A, const float* __restrict__ W,
    float* __restrict__ part)
{
    const int n0 = blockIdx.x * 64;
    const int s  = blockIdx.y;
    const int kbase = s * 2048;
    const int tid = threadIdx.x;
    __shared__ float As[32][68];
    __shared__ float Bs[32][68];
    const int tm = tid >> 4, tn = tid & 15;
    float acc[4][4] = {};

    for (int kt = 0; kt < 2048; kt += 32) {
        #pragma unroll
        for (int q = tid; q < 512; q += 256) {
            const int mm = q >> 3;
            const int kq = q & 7;
            uint4 v = *(const uint4*)&A[(size_t)mm * KFLAT + kbase + kt + kq * 4];
            As[kq*4+0][mm] = pk2f(v.x & 0xFFFFFFF0u); As[kq*4+1][mm] = pk2f(v.y & 0xFFFFFFF0u);
            As[kq*4+2][mm] = pk2f(v.z & 0xFFFFFFF0u); As[kq*4+3][mm] = pk2f(v.w & 0xFFFFFFF0u);
            float4 w = *(const float4*)&W[(size_t)(n0 + mm) * KFLAT + kbase + kt + kq * 4];
            Bs[kq*4+0][mm] = w.x; Bs[kq*4+1][mm] = w.y;
            Bs[kq*4+2][mm] = w.z; Bs[kq*4+3][mm] = w.w;
        }
        __syncthreads();
        #pragma unroll
        for (int k = 0; k < 32; ++k) {
            float4 a = *(const float4*)&As[k][tm * 4];
            float4 b = *(const float4*)&Bs[k][tn * 4];
            acc[0][0] += a.x*b.x; acc[0][1] += a.x*b.y; acc[0][2] += a.x*b.z; acc[0][3] += a.x*b.w;
            acc[1][0] += a.y*b.x; acc[1][1] += a.y*b.y; acc[1][2] += a.y*b.z; acc[1][3] += a.y*b.w;
            acc[2][0] += a.z*b.x; acc[2][1] += a.z*b.y; acc[2][2] += a.z*b.z; acc[2][3] += a.z*b.w;
            acc[3][0] += a.w*b.x; acc[3][1] += a.w*b.y; acc[3][2] += a.w*b.z; acc[3][3] += a.w*b.w;
        }
        __syncthreads();
    }
    #pragma unroll
    for (int i = 0; i < 4; ++i) {
        const int m = tm * 4 + i;
        #pragma unroll
        for (int j = 0; j < 4; ++j) {
            part[((size_t)s * 64 + m) * 512 + n0 + tn * 4 + j] = acc[i][j];
        }
    }
}

// ---------------------------------------------------------------------------
// Classifier finish (unchanged)
// ---------------------------------------------------------------------------
__global__ __launch_bounds__(256) void cls_final_kernel(
    const float* __restrict__ part, const float* __restrict__ b1,
    const float* __restrict__ w2, const float* __restrict__ b2,
    float* __restrict__ out)
{
    const int t = blockIdx.x;
    __shared__ float hm[512];
    for (int n = threadIdx.x; n < 512; n += 256) {
        float sacc = b1[n];
        for (int sl = 0; sl < 32; ++sl)
            sacc += part[((size_t)sl * 64 + t) * 512 + n];
        hm[n] = fmaxf(sacc, 0.f);
    }
    __syncthreads();
    if (threadIdx.x < NCC) {
        float sacc = b2[threadIdx.x];
        const float* wr = w2 + (size_t)threadIdx.x * 512;
        for (int n = 0; n < 512; ++n) sacc += hm[n] * wr[n];
        out[t * NCC + threadIdx.x] = sacc;
    }
}

// ---------------------------------------------------------------------------
extern "C" void kernel_launch(void* const* d_in, const int* in_sizes, int n_in,
                              void* d_out, int out_size, void* d_ws, size_t ws_size,
                              hipStream_t stream)
{
    const float* x     = (const float*)d_in[0];
    const float* w_ih0 = (const float*)d_in[1];
    const float* w_hh0 = (const float*)d_in[2];
    const float* b_ih0 = (const float*)d_in[3];
    const float* b_hh0 = (const float*)d_in[4];
    const float* w_ih1 = (const float*)d_in[5];
    const float* w_hh1 = (const float*)d_in[6];
    const float* b_ih1 = (const float*)d_in[7];
    const float* b_hh1 = (const float*)d_in[8];
    const float* w1    = (const float*)d_in[9];
    const float* b1    = (const float*)d_in[10];
    const float* w2    = (const float*)d_in[11];
    const float* b2    = (const float*)d_in[12];
    float* out = (float*)d_out;

    // Workspace (~102.1 MB): hpack1 region is ALIASED over xpk/w0pk (dead
    // after the layer-0 GEMM). All t>=1 h reads are flag-gated (flags
    // zeroed each launch) and tag-checked, so no 0xFF scrub is needed.
    // flags alias the part region (part written only after lstm_fused).
    float*    ws     = (float*)d_ws;
    float*    xg     = ws;                                      // 64 MB
    unsigned* hpack0 = (unsigned*)(xg + (size_t)8192 * 2048);   // 17.04 MB
    unsigned* hpack1 = hpack0 + (size_t)65 * BB * HH;           // 17.04 MB (aliased)
    unsigned* xpk    = hpack1;                                  // 8 MB   (dies at GEMM)
    unsigned* w0pk   = xpk + (size_t)8192 * IND;                // 2 MB   (dies at GEMM)
    float*    part   = (float*)(hpack1 + (size_t)65 * BB * HH); // 4 MB
    unsigned* flags  = (unsigned*)part;                         // 66.6 KB (dies at cls)

    // ---- pack layer-0 GEMM inputs ----
    pack_split_kernel<<<1024, 256, 0, stream>>>(x, xpk, 8192 * IND);
    pack_split_kernel<<<512,  256, 0, stream>>>(w_ih0, w0pk, GG * IND);
    hipMemsetAsync(hpack0, 0, (size_t)BB * HH * sizeof(unsigned), stream);  // h0 t=0
    hipMemsetAsync(flags, 0, (size_t)2 * 65 * 4 * 32 * sizeof(unsigned), stream);

    // ---- layer-0 input transform ----
    gemm_pk_mfma<<<dim3(8192 / 128, GG / 128), 256, 0, stream>>>(
        xpk, w0pk, b_ih0, b_hh0, xg, IND, GG);

    // ---- zero t=0 block of hpack1 (after GEMM: aliased region now dead) ----
    hipMemsetAsync(hpack1, 0, (size_t)BB * HH * sizeof(unsigned), stream);

    // ---- fused two-layer recurrence ----
    lstm_fused<<<256, 256, 0, stream>>>(
        xg, w_hh0, w_ih1, w_hh1, b_ih1, b_hh1, hpack0, hpack1, flags);

    // ---- classifier (tagged h1, blocks 1..64) ----
    cls_partial_kernel<<<dim3(512 / 64, 32), 256, 0, stream>>>(
        hpack1 + (size_t)BB * HH, w1, part);
    cls_final_kernel<<<64, 256, 0, stream>>>(part, b1, w2, b2, out);
}

// Round 3
// 912.502 us; speedup vs baseline: 1.6469x; 1.0826x over previous
//
#include <hip/hip_runtime.h>

// Problem constants (reference: T=64 time steps, B=SEQ=128 batch, IN=256, H=512)
#define TT 64
#define BB 128
#define IND 256
#define HH 512
#define GG 2048      // 4*H
#define NCC 10
#define KFLAT 65536  // SEQ*H
#define HP2 520      // bf16 LDS row stride (512 + 8)
#define SP 36        // GEMM LDS short stride

typedef __attribute__((ext_vector_type(8))) short bf16x8;
typedef __attribute__((ext_vector_type(4))) float floatx4;

__device__ __forceinline__ unsigned short f2bf(float x) {   // RNE round to bf16
    unsigned u = __builtin_bit_cast(unsigned, x);
    u += 0x7fffu + ((u >> 16) & 1u);
    return (unsigned short)(u >> 16);
}
__device__ __forceinline__ float bf2f(unsigned short h) {
    unsigned u = ((unsigned)h) << 16;
    return __builtin_bit_cast(float, u);
}
__device__ __forceinline__ float pk2f(unsigned u) {
    float hi = __builtin_bit_cast(float, u & 0xffff0000u);
    float lo = __builtin_bit_cast(float, u << 16);
    return hi + lo;
}

// ---------------------------------------------------------------------------
// Elementwise: fp32 -> packed split-bf16 (hi<<16 | lo)
// ---------------------------------------------------------------------------
__global__ __launch_bounds__(256) void pack_split_kernel(
    const float* __restrict__ src, unsigned* __restrict__ dst, int n)
{
    for (int i = blockIdx.x * 256 + threadIdx.x; i < n; i += gridDim.x * 256) {
        float f = src[i];
        unsigned short hb = f2bf(f);
        unsigned short lb = f2bf(f - bf2f(hb));
        dst[i] = ((unsigned)hb << 16) | lb;
    }
}

// ---------------------------------------------------------------------------
// MFMA GEMM on packed split-bf16 (proven R6): layer-0 input transform only.
// ---------------------------------------------------------------------------
__global__ __launch_bounds__(256) void gemm_pk_mfma(
    const unsigned* __restrict__ A, const unsigned* __restrict__ W,
    const float* __restrict__ b0, const float* __restrict__ b1,
    float* __restrict__ C, int K, int N)
{
    __shared__ short Ahi[128][SP], Alo[128][SP], Whi[128][SP], Wlo[128][SP];

    const int tid  = threadIdx.x;
    const int lane = tid & 63;
    const int wv   = tid >> 6;
    const int wm   = (wv & 1) * 64;
    const int wn   = (wv >> 1) * 64;
    const int l15  = lane & 15;
    const int quad = lane >> 4;
    const int m0   = blockIdx.x * 128;
    const int n0   = blockIdx.y * 128;

    floatx4 acc[4][4];
    #pragma unroll
    for (int i = 0; i < 4; ++i)
        #pragma unroll
        for (int j = 0; j < 4; ++j)
            acc[i][j] = (floatx4){0.f, 0.f, 0.f, 0.f};

    for (int kc = 0; kc < K; kc += 32) {
        #pragma unroll
        for (int it = 0; it < 4; ++it) {
            const int lin = it * 256 + tid;
            const int row = lin >> 3;
            const int c4  = (lin & 7) * 4;
            uint4 va = *(const uint4*)&A[(size_t)(m0 + row) * K + kc + c4];
            uint2 ah, al;
            ah.x = (va.x >> 16) | (va.y & 0xffff0000u);
            ah.y = (va.z >> 16) | (va.w & 0xffff0000u);
            al.x = (va.x & 0xffffu) | (va.y << 16);
            al.y = (va.z & 0xffffu) | (va.w << 16);
            *(uint2*)&Ahi[row][c4] = ah;
            *(uint2*)&Alo[row][c4] = al;
            uint4 vw = *(const uint4*)&W[(size_t)(n0 + row) * K + kc + c4];
            uint2 wh, wl;
            wh.x = (vw.x >> 16) | (vw.y & 0xffff0000u);
            wh.y = (vw.z >> 16) | (vw.w & 0xffff0000u);
            wl.x = (vw.x & 0xffffu) | (vw.y << 16);
            wl.y = (vw.z & 0xffffu) | (vw.w << 16);
            *(uint2*)&Whi[row][c4] = wh;
            *(uint2*)&Wlo[row][c4] = wl;
        }
        __syncthreads();

        bf16x8 afh[4], afl[4], bfh[4], bfl[4];
        #pragma unroll
        for (int i = 0; i < 4; ++i) {
            afh[i] = *(const bf16x8*)&Ahi[wm + i * 16 + l15][quad * 8];
            afl[i] = *(const bf16x8*)&Alo[wm + i * 16 + l15][quad * 8];
            bfh[i] = *(const bf16x8*)&Whi[wn + i * 16 + l15][quad * 8];
            bfl[i] = *(const bf16x8*)&Wlo[wn + i * 16 + l15][quad * 8];
        }
        #pragma unroll
        for (int i = 0; i < 4; ++i)
            #pragma unroll
            for (int j = 0; j < 4; ++j) {
                acc[i][j] = __builtin_amdgcn_mfma_f32_16x16x32_bf16(afh[i], bfh[j], acc[i][j], 0, 0, 0);
                acc[i][j] = __builtin_amdgcn_mfma_f32_16x16x32_bf16(afh[i], bfl[j], acc[i][j], 0, 0, 0);
                acc[i][j] = __builtin_amdgcn_mfma_f32_16x16x32_bf16(afl[i], bfh[j], acc[i][j], 0, 0, 0);
            }
        __syncthreads();
    }

    #pragma unroll
    for (int i = 0; i < 4; ++i) {
        #pragma unroll
        for (int j = 0; j < 4; ++j) {
            const int n = n0 + wn + j * 16 + l15;
            const float bias = b0[n] + b1[n];
            #pragma unroll
            for (int r = 0; r < 4; ++r) {
                const int m = m0 + wm + i * 16 + quad * 4 + r;
                C[(size_t)m * N + n] = acc[i][j][r] + bias;
            }
        }
    }
}

// ---------------------------------------------------------------------------
// Stage 8 tagged h-cells into LDS hi/lo planes — ATOMIC (L2-bypassing) path.
// Used only as the retry fallback; returns nonzero on tag miss.
// ---------------------------------------------------------------------------
__device__ __forceinline__ unsigned stage8_atomic(
    const unsigned long long* __restrict__ src, int bb, int kk, unsigned exp,
    short (*Hs_hi)[HP2], short (*Hs_lo)[HP2])
{
    unsigned long long q0 = __hip_atomic_load(src + 0, __ATOMIC_RELAXED, __HIP_MEMORY_SCOPE_AGENT);
    unsigned long long q1 = __hip_atomic_load(src + 1, __ATOMIC_RELAXED, __HIP_MEMORY_SCOPE_AGENT);
    unsigned long long q2 = __hip_atomic_load(src + 2, __ATOMIC_RELAXED, __HIP_MEMORY_SCOPE_AGENT);
    unsigned long long q3 = __hip_atomic_load(src + 3, __ATOMIC_RELAXED, __HIP_MEMORY_SCOPE_AGENT);
    unsigned c0 = (unsigned)q0, c1 = (unsigned)(q0 >> 32);
    unsigned c2 = (unsigned)q1, c3 = (unsigned)(q1 >> 32);
    unsigned c4 = (unsigned)q2, c5 = (unsigned)(q2 >> 32);
    unsigned c6 = (unsigned)q3, c7 = (unsigned)(q3 >> 32);
    unsigned bad = ((c0 ^ exp) | (c1 ^ exp) | (c2 ^ exp) | (c3 ^ exp)
                  | (c4 ^ exp) | (c5 ^ exp) | (c6 ^ exp) | (c7 ^ exp)) & 0xFu;
    uint4 hiv, lov;
    hiv.x = (c0 >> 16) | (c1 & 0xffff0000u);
    hiv.y = (c2 >> 16) | (c3 & 0xffff0000u);
    hiv.z = (c4 >> 16) | (c5 & 0xffff0000u);
    hiv.w = (c6 >> 16) | (c7 & 0xffff0000u);
    lov.x = (c0 & 0xFFF0u) | ((c1 & 0xFFF0u) << 16);
    lov.y = (c2 & 0xFFF0u) | ((c3 & 0xFFF0u) << 16);
    lov.z = (c4 & 0xFFF0u) | ((c5 & 0xFFF0u) << 16);
    lov.w = (c6 & 0xFFF0u) | ((c7 & 0xFFF0u) << 16);
    *(uint4*)&Hs_hi[bb][kk] = hiv;
    *(uint4*)&Hs_lo[bb][kk] = lov;
    return bad;
}

// ---------------------------------------------------------------------------
// Stage 8 tagged h-cells — PLAIN CACHED path (fast). Only issued after the
// flag handshake; tag check retained, mismatch retries via stage8_atomic.
// ---------------------------------------------------------------------------
__device__ __forceinline__ unsigned stage8_plain(
    const unsigned* __restrict__ src, int bb, int kk, unsigned exp,
    short (*Hs_hi)[HP2], short (*Hs_lo)[HP2])
{
    const uint4 v0 = *(const uint4*)(src);
    const uint4 v1 = *(const uint4*)(src + 4);
    unsigned bad = ((v0.x ^ exp) | (v0.y ^ exp) | (v0.z ^ exp) | (v0.w ^ exp)
                  | (v1.x ^ exp) | (v1.y ^ exp) | (v1.z ^ exp) | (v1.w ^ exp)) & 0xFu;
    uint4 hiv, lov;
    hiv.x = (v0.x >> 16) | (v0.y & 0xffff0000u);
    hiv.y = (v0.z >> 16) | (v0.w & 0xffff0000u);
    hiv.z = (v1.x >> 16) | (v1.y & 0xffff0000u);
    hiv.w = (v1.z >> 16) | (v1.w & 0xffff0000u);
    lov.x = (v0.x & 0xFFF0u) | ((v0.y & 0xFFF0u) << 16);
    lov.y = (v0.z & 0xFFF0u) | ((v0.w & 0xFFF0u) << 16);
    lov.z = (v1.x & 0xFFF0u) | ((v1.y & 0xFFF0u) << 16);
    lov.w = (v1.z & 0xFFF0u) | ((v1.w & 0xFFF0u) << 16);
    *(uint4*)&Hs_hi[bb][kk] = hiv;
    *(uint4*)&Hs_lo[bb][kk] = lov;
    return bad;
}

// Full-tile stage: plain cached pass + atomic retry fallback.
__device__ __forceinline__ void stage_tile(
    const unsigned* __restrict__ base, unsigned exp, int tid,
    short (*Hs_hi)[HP2], short (*Hs_lo)[HP2])
{
    unsigned miss = 0;
    #pragma unroll
    for (int p = 0; p < 8; ++p) {
        const int idx = p * 2048 + tid * 8;
        unsigned bad = stage8_plain(base + idx, idx >> 9, idx & 511,
                                    exp, Hs_hi, Hs_lo);
        miss |= (bad ? 1u : 0u) << p;
    }
    while (miss) {
        #pragma unroll
        for (int p = 0; p < 8; ++p) {
            if (miss & (1u << p)) {
                const int idx = p * 2048 + tid * 8;
                if (!stage8_atomic((const unsigned long long*)(base + idx),
                                   idx >> 9, idx & 511, exp, Hs_hi, Hs_lo))
                    miss &= ~(1u << p);
            }
        }
    }
}

// Agent-scope relaxed poll (L2-bypassing; observes the coherence point).
__device__ __forceinline__ void spin_flag(const unsigned* p) {
    while (__hip_atomic_load(p, __ATOMIC_RELAXED, __HIP_MEMORY_SCOPE_AGENT) == 0u) { }
}

// ---------------------------------------------------------------------------
// FUSED two-layer persistent LSTM. Blocks 0..127 = layer 0; blocks
// 128..255 = layer 1 (runs >=1 step behind, self-timed). WG (bt, j0):
// batches [bt*32,+32) x 16 hidden units x 4 gates (wave g = gate g).
//
// R3 critical-path restructure:
//  * layer-1 X phase FIRST: poll fX (already set in steady state: layer-0
//    runs ahead) -> stage X -> X-MFMAs, all BEFORE polling fR. Only the
//    recurrent R phase (stage + 96 MFMAs + update + drain + flag + detect)
//    remains on the serial h1 chain.
//  * single-wave polling: wave 0 polls, other waves wait at the barrier —
//    cuts the chip-wide agent-scope poll storm 4x (it inflates latency of
//    the store-ACK/flag/fill traffic that IS the critical chain).
// Sync protocol unchanged from R2 (proven): tagged relaxed-agent h stores,
// barrier drain, relaxed-agent flag store; consumers flag-gate then stage
// with plain cached loads; tags catch any residual staleness.
// ---------------------------------------------------------------------------
__global__ __launch_bounds__(256, 1) void lstm_fused(
    const float* __restrict__ xg,     // [T][B][4H] layer-0 (biases included)
    const float* __restrict__ w_hh0,  // [4H][H] fp32
    const float* __restrict__ w_ih1,  // [4H][H] fp32
    const float* __restrict__ w_hh1,  // [4H][H] fp32
    const float* __restrict__ b_ih1, const float* __restrict__ b_hh1,
    unsigned* __restrict__ hpack0,    // [T+1][B][H] tagged, block 0 zeroed
    unsigned* __restrict__ hpack1,    // [T+1][B][H] tagged, block 0 zeroed
    unsigned* __restrict__ flags)     // [2][T+1][4][32] step flags (zeroed)
{
    __shared__ short Ra_hi[32][HP2], Ra_lo[32][HP2];   // recurrent h tile
    __shared__ short Xa_hi[32][HP2], Xa_lo[32][HP2];   // layer-1 input h0 tile
    __shared__ float Gs[64][33];

    const int tid  = threadIdx.x;
    const int lane = tid & 63;
    const int wv   = tid >> 6;               // wave = gate 0..3
    const bool isB = blockIdx.x >= 128;
    const int blk  = blockIdx.x & 127;
    const int bt   = blk & 3;
    const int jsl  = blk >> 2;               // producer j-slice id 0..31
    const int j0   = jsl * 16;               // 16-unit slice
    const int l15  = lane & 15;
    const int quad = lane >> 4;

    // ---- preload recurrent-weight frags (16 rows: gate wv, units j0+l15) ----
    bf16x8 wa_hi[16], wa_lo[16], wx_hi[16], wx_lo[16];
    {
        const float* wsrc = isB ? w_hh1 : w_hh0;
        const float* wrow = wsrc + (size_t)(wv * HH + j0 + l15) * HH + quad * 8;
        #pragma unroll
        for (int kc = 0; kc < 16; ++kc) {
            float f[8];
            *(float4*)&f[0] = *(const float4*)&wrow[kc * 32];
            *(float4*)&f[4] = *(const float4*)&wrow[kc * 32 + 4];
            bf16x8 vh, vl;
            #pragma unroll
            for (int j = 0; j < 8; ++j) {
                unsigned short hb = f2bf(f[j]);
                vh[j] = (short)hb;
                vl[j] = (short)f2bf(f[j] - bf2f(hb));
            }
            wa_hi[kc] = vh; wa_lo[kc] = vl;
        }
        if (isB) {
            const float* xrow = w_ih1 + (size_t)(wv * HH + j0 + l15) * HH + quad * 8;
            #pragma unroll
            for (int kc = 0; kc < 16; ++kc) {
                float f[8];
                *(float4*)&f[0] = *(const float4*)&xrow[kc * 32];
                *(float4*)&f[4] = *(const float4*)&xrow[kc * 32 + 4];
                bf16x8 vh, vl;
                #pragma unroll
                for (int j = 0; j < 8; ++j) {
                    unsigned short hb = f2bf(f[j]);
                    vh[j] = (short)hb;
                    vl[j] = (short)f2bf(f[j] - bf2f(hb));
                }
                wx_hi[kc] = vh; wx_lo[kc] = vl;
            }
        }
    }

    // update-phase roles: (j_u, bu) and (j_u, bu+16)
    const int j_u = tid & 15;
    const int bu  = tid >> 4;          // 0..15
    float bias_i = 0.f, bias_f = 0.f, bias_g = 0.f, bias_o = 0.f;
    if (isB) {
        bias_i = b_ih1[j0 + j_u]            + b_hh1[j0 + j_u];
        bias_f = b_ih1[HH + j0 + j_u]       + b_hh1[HH + j0 + j_u];
        bias_g = b_ih1[2 * HH + j0 + j_u]   + b_hh1[2 * HH + j0 + j_u];
        bias_o = b_ih1[3 * HH + j0 + j_u]   + b_hh1[3 * HH + j0 + j_u];
    }

    unsigned* hp_rec = isB ? hpack1 : hpack0;
    const int layerBase = isB ? 65 : 0;
    float c0 = 0.f, c1 = 0.f;

    for (int t = 0; t < TT; ++t) {
        const unsigned* rec_base = hp_rec + (size_t)t * (BB * HH) + (size_t)bt * 32 * HH;
        const unsigned* inp_base = hpack0 + (size_t)(t + 1) * (BB * HH) + (size_t)bt * 32 * HH;
        const unsigned expR = (unsigned)t % 9u;
        const unsigned expX = (unsigned)(t + 1) % 9u;
        const unsigned* fR = flags + ((layerBase + t) * 4 + bt) * 32;
        const unsigned* fX = flags + ((t + 1) * 4 + bt) * 32;

        floatx4 a0 = {0.f,0.f,0.f,0.f}, a1 = {0.f,0.f,0.f,0.f};
        float xgv[2][4];

        if (isB) {
            // ======== X phase (OFF the recurrent critical path) ========
            if (wv == 0 && lane < 32) spin_flag(fX + lane);
            __syncthreads();
            stage_tile(inp_base, expX, tid, Xa_hi, Xa_lo);
            __syncthreads();
            #pragma unroll
            for (int kc = 0; kc < 16; ++kc) {
                const int off = kc * 32 + quad * 8;
                bf16x8 x0h = *(const bf16x8*)&Xa_hi[l15][off];
                bf16x8 x0l = *(const bf16x8*)&Xa_lo[l15][off];
                bf16x8 x1h = *(const bf16x8*)&Xa_hi[16 + l15][off];
                bf16x8 x1l = *(const bf16x8*)&Xa_lo[16 + l15][off];
                a0 = __builtin_amdgcn_mfma_f32_16x16x32_bf16(wx_hi[kc], x0h, a0, 0, 0, 0);
                a1 = __builtin_amdgcn_mfma_f32_16x16x32_bf16(wx_hi[kc], x1h, a1, 0, 0, 0);
                a0 = __builtin_amdgcn_mfma_f32_16x16x32_bf16(wx_hi[kc], x0l, a0, 0, 0, 0);
                a1 = __builtin_amdgcn_mfma_f32_16x16x32_bf16(wx_hi[kc], x1l, a1, 0, 0, 0);
                a0 = __builtin_amdgcn_mfma_f32_16x16x32_bf16(wx_lo[kc], x0h, a0, 0, 0, 0);
                a1 = __builtin_amdgcn_mfma_f32_16x16x32_bf16(wx_lo[kc], x1h, a1, 0, 0, 0);
            }
            // ======== R phase (the serial h1 chain) ========
            if (wv == 0 && lane < 32 && t > 0 && lane != jsl) spin_flag(fR + lane);
            __syncthreads();
            stage_tile(rec_base, expR, tid, Ra_hi, Ra_lo);
            __syncthreads();
        } else {
            // layer-0: xg prefetch overlaps poll + staging latency
            #pragma unroll
            for (int ccell = 0; ccell < 2; ++ccell) {
                const int b = bu + ccell * 16;
                const float* base = xg + (size_t)t * (BB * GG)
                                  + (size_t)(bt * 32 + b) * GG + j0 + j_u;
                xgv[ccell][0] = base[0];
                xgv[ccell][1] = base[HH];
                xgv[ccell][2] = base[2 * HH];
                xgv[ccell][3] = base[3 * HH];
            }
            if (wv == 0 && lane < 32 && t > 0 && lane != jsl) spin_flag(fR + lane);
            __syncthreads();
            stage_tile(rec_base, expR, tid, Ra_hi, Ra_lo);
            __syncthreads();
        }

        // ---- R MFMAs (both layers) ----
        #pragma unroll
        for (int kc = 0; kc < 16; ++kc) {
            const int off = kc * 32 + quad * 8;
            bf16x8 r0h = *(const bf16x8*)&Ra_hi[l15][off];
            bf16x8 r0l = *(const bf16x8*)&Ra_lo[l15][off];
            bf16x8 r1h = *(const bf16x8*)&Ra_hi[16 + l15][off];
            bf16x8 r1l = *(const bf16x8*)&Ra_lo[16 + l15][off];
            a0 = __builtin_amdgcn_mfma_f32_16x16x32_bf16(wa_hi[kc], r0h, a0, 0, 0, 0);
            a1 = __builtin_amdgcn_mfma_f32_16x16x32_bf16(wa_hi[kc], r1h, a1, 0, 0, 0);
            a0 = __builtin_amdgcn_mfma_f32_16x16x32_bf16(wa_hi[kc], r0l, a0, 0, 0, 0);
            a1 = __builtin_amdgcn_mfma_f32_16x16x32_bf16(wa_hi[kc], r1l, a1, 0, 0, 0);
            a0 = __builtin_amdgcn_mfma_f32_16x16x32_bf16(wa_lo[kc], r0h, a0, 0, 0, 0);
            a1 = __builtin_amdgcn_mfma_f32_16x16x32_bf16(wa_lo[kc], r1h, a1, 0, 0, 0);
        }

        // ---- exchange preacts: rows = gate*16 + unit(quad*4+r) ----
        #pragma unroll
        for (int r = 0; r < 4; ++r) {
            Gs[wv * 16 + quad * 4 + r][l15]      = a0[r];
            Gs[wv * 16 + quad * 4 + r][16 + l15] = a1[r];
        }
        __syncthreads();

        // ---- elementwise update for 2 cells; tagged fire-and-forget store ----
        const unsigned tag = (unsigned)(t + 1) % 9u;
        #pragma unroll
        for (int ccell = 0; ccell < 2; ++ccell) {
            const int b = bu + ccell * 16;
            float gi = Gs[j_u][b],      gf = Gs[16 + j_u][b];
            float gg = Gs[32 + j_u][b], go = Gs[48 + j_u][b];
            if (isB) { gi += bias_i; gf += bias_f; gg += bias_g; go += bias_o; }
            else     { gi += xgv[ccell][0]; gf += xgv[ccell][1];
                       gg += xgv[ccell][2]; go += xgv[ccell][3]; }
            const float si = 1.f / (1.f + __expf(-gi));
            const float sf = 1.f / (1.f + __expf(-gf));
            const float tg = 2.f / (1.f + __expf(-2.f * gg)) - 1.f;
            const float so = 1.f / (1.f + __expf(-go));
            float& cr = ccell ? c1 : c0;
            cr = sf * cr + si * tg;
            const float th = 2.f / (1.f + __expf(-2.f * cr)) - 1.f;
            const float hval = so * th;
            const unsigned short hb = f2bf(hval);
            const unsigned short lb = f2bf(hval - bf2f(hb));
            const unsigned pk = ((unsigned)hb << 16) | ((unsigned)lb & 0xFFF0u) | tag;
            __hip_atomic_store(
                &hp_rec[(size_t)(t + 1) * (BB * HH) + (size_t)(bt * 32 + b) * HH + j0 + j_u],
                pk, __ATOMIC_RELAXED, __HIP_MEMORY_SCOPE_AGENT);
        }
        __syncthreads();   // drains every lane's h stores (vmcnt 0)

        // ---- publish: flag store for this slice (after the drain) ----
        if (tid == 0)
            __hip_atomic_store(
                flags + ((layerBase + (t + 1)) * 4 + bt) * 32 + jsl,
                1u, __ATOMIC_RELAXED, __HIP_MEMORY_SCOPE_AGENT);
    }
}

// ---------------------------------------------------------------------------
// Classifier split-K partial GEMM on tagged h cells (mask tag nibble)
// ---------------------------------------------------------------------------
__global__ __launch_bounds__(256) void cls_partial_kernel(
    const unsigned* __restrict__ A, const float* __restrict__ W,
    float* __restrict__ part)
{
    const int n0 = blockIdx.x * 64;
    const int s  = blockIdx.y;
    const int kbase = s * 2048;
    const int tid = threadIdx.x;
    __shared__ float As[32][68];
    __shared__ float Bs[32][68];
    const int tm = tid >> 4, tn = tid & 15;
    float acc[4][4] = {};

    for (int kt = 0; kt < 2048; kt += 32) {
        #pragma unroll
        for (int q = tid; q < 512; q += 256) {
            const int mm = q >> 3;
            const int kq = q & 7;
            uint4 v = *(const uint4*)&A[(size_t)mm * KFLAT + kbase + kt + kq * 4];
            As[kq*4+0][mm] = pk2f(v.x & 0xFFFFFFF0u); As[kq*4+1][mm] = pk2f(v.y & 0xFFFFFFF0u);
            As[kq*4+2][mm] = pk2f(v.z & 0xFFFFFFF0u); As[kq*4+3][mm] = pk2f(v.w & 0xFFFFFFF0u);
            float4 w = *(const float4*)&W[(size_t)(n0 + mm) * KFLAT + kbase + kt + kq * 4];
            Bs[kq*4+0][mm] = w.x; Bs[kq*4+1][mm] = w.y;
            Bs[kq*4+2][mm] = w.z; Bs[kq*4+3][mm] = w.w;
        }
        __syncthreads();
        #pragma unroll
        for (int k = 0; k < 32; ++k) {
            float4 a = *(const float4*)&As[k][tm * 4];
            float4 b = *(const float4*)&Bs[k][tn * 4];
            acc[0][0] += a.x*b.x; acc[0][1] += a.x*b.y; acc[0][2] += a.x*b.z; acc[0][3] += a.x*b.w;
            acc[1][0] += a.y*b.x; acc[1][1] += a.y*b.y; acc[1][2] += a.y*b.z; acc[1][3] += a.y*b.w;
            acc[2][0] += a.z*b.x; acc[2][1] += a.z*b.y; acc[2][2] += a.z*b.z; acc[2][3] += a.z*b.w;
            acc[3][0] += a.w*b.x; acc[3][1] += a.w*b.y; acc[3][2] += a.w*b.z; acc[3][3] += a.w*b.w;
        }
        __syncthreads();
    }
    #pragma unroll
    for (int i = 0; i < 4; ++i) {
        const int m = tm * 4 + i;
        #pragma unroll
        for (int j = 0; j < 4; ++j) {
            part[((size_t)s * 64 + m) * 512 + n0 + tn * 4 + j] = acc[i][j];
        }
    }
}

// ---------------------------------------------------------------------------
// Classifier finish (unchanged)
// ---------------------------------------------------------------------------
__global__ __launch_bounds__(256) void cls_final_kernel(
    const float* __restrict__ part, const float* __restrict__ b1,
    const float* __restrict__ w2, const float* __restrict__ b2,
    float* __restrict__ out)
{
    const int t = blockIdx.x;
    __shared__ float hm[512];
    for (int n = threadIdx.x; n < 512; n += 256) {
        float sacc = b1[n];
        for (int sl = 0; sl < 32; ++sl)
            sacc += part[((size_t)sl * 64 + t) * 512 + n];
        hm[n] = fmaxf(sacc, 0.f);
    }
    __syncthreads();
    if (threadIdx.x < NCC) {
        float sacc = b2[threadIdx.x];
        const float* wr = w2 + (size_t)threadIdx.x * 512;
        for (int n = 0; n < 512; ++n) sacc += hm[n] * wr[n];
        out[t * NCC + threadIdx.x] = sacc;
    }
}

// ---------------------------------------------------------------------------
extern "C" void kernel_launch(void* const* d_in, const int* in_sizes, int n_in,
                              void* d_out, int out_size, void* d_ws, size_t ws_size,
                              hipStream_t stream)
{
    const float* x     = (const float*)d_in[0];
    const float* w_ih0 = (const float*)d_in[1];
    const float* w_hh0 = (const float*)d_in[2];
    const float* b_ih0 = (const float*)d_in[3];
    const float* b_hh0 = (const float*)d_in[4];
    const float* w_ih1 = (const float*)d_in[5];
    const float* w_hh1 = (const float*)d_in[6];
    const float* b_ih1 = (const float*)d_in[7];
    const float* b_hh1 = (const float*)d_in[8];
    const float* w1    = (const float*)d_in[9];
    const float* b1    = (const float*)d_in[10];
    const float* w2    = (const float*)d_in[11];
    const float* b2    = (const float*)d_in[12];
    float* out = (float*)d_out;

    // Workspace (~102.1 MB): hpack1 region is ALIASED over xpk/w0pk (dead
    // after the layer-0 GEMM). All t>=1 h reads are flag-gated (flags
    // zeroed each launch) and tag-checked, so no 0xFF scrub is needed.
    // flags alias the part region (part written only after lstm_fused).
    float*    ws     = (float*)d_ws;
    float*    xg     = ws;                                      // 64 MB
    unsigned* hpack0 = (unsigned*)(xg + (size_t)8192 * 2048);   // 17.04 MB
    unsigned* hpack1 = hpack0 + (size_t)65 * BB * HH;           // 17.04 MB (aliased)
    unsigned* xpk    = hpack1;                                  // 8 MB   (dies at GEMM)
    unsigned* w0pk   = xpk + (size_t)8192 * IND;                // 2 MB   (dies at GEMM)
    float*    part   = (float*)(hpack1 + (size_t)65 * BB * HH); // 4 MB
    unsigned* flags  = (unsigned*)part;                         // 66.6 KB (dies at cls)

    // ---- pack layer-0 GEMM inputs ----
    pack_split_kernel<<<1024, 256, 0, stream>>>(x, xpk, 8192 * IND);
    pack_split_kernel<<<512,  256, 0, stream>>>(w_ih0, w0pk, GG * IND);
    hipMemsetAsync(hpack0, 0, (size_t)BB * HH * sizeof(unsigned), stream);  // h0 t=0
    hipMemsetAsync(flags, 0, (size_t)2 * 65 * 4 * 32 * sizeof(unsigned), stream);

    // ---- layer-0 input transform ----
    gemm_pk_mfma<<<dim3(8192 / 128, GG / 128), 256, 0, stream>>>(
        xpk, w0pk, b_ih0, b_hh0, xg, IND, GG);

    // ---- zero t=0 block of hpack1 (after GEMM: aliased region now dead) ----
    hipMemsetAsync(hpack1, 0, (size_t)BB * HH * sizeof(unsigned), stream);

    // ---- fused two-layer recurrence ----
    lstm_fused<<<256, 256, 0, stream>>>(
        xg, w_hh0, w_ih1, w_hh1, b_ih1, b_hh1, hpack0, hpack1, flags);

    // ---- classifier (tagged h1, blocks 1..64) ----
    cls_partial_kernel<<<dim3(512 / 64, 32), 256, 0, stream>>>(
        hpack1 + (size_t)BB * HH, w1, part);
    cls_final_kernel<<<64, 256, 0, stream>>>(part, b1, w2, b2, out);
}

// Round 5
// 818.467 us; speedup vs baseline: 1.8361x; 1.1149x over previous
//
#include <hip/hip_runtime.h>

// Problem constants (reference: T=64 time steps, B=SEQ=128 batch, IN=256, H=512)
#define TT 64
#define BB 128
#define IND 256
#define HH 512
#define GG 2048      // 4*H
#define NCC 10
#define KFLAT 65536  // SEQ*H
#define HP2 520      // bf16 LDS row stride (512 + 8)
#define SP 36        // GEMM LDS short stride

typedef __attribute__((ext_vector_type(8))) short bf16x8;
typedef __attribute__((ext_vector_type(4))) float floatx4;

__device__ __forceinline__ unsigned short f2bf(float x) {   // RNE round to bf16
    unsigned u = __builtin_bit_cast(unsigned, x);
    u += 0x7fffu + ((u >> 16) & 1u);
    return (unsigned short)(u >> 16);
}
__device__ __forceinline__ float bf2f(unsigned short h) {
    unsigned u = ((unsigned)h) << 16;
    return __builtin_bit_cast(float, u);
}
__device__ __forceinline__ float pk2f(unsigned u) {
    float hi = __builtin_bit_cast(float, u & 0xffff0000u);
    float lo = __builtin_bit_cast(float, u << 16);
    return hi + lo;
}

// ---------------------------------------------------------------------------
// Elementwise: fp32 -> packed split-bf16 (hi<<16 | lo)
// ---------------------------------------------------------------------------
__global__ __launch_bounds__(256) void pack_split_kernel(
    const float* __restrict__ src, unsigned* __restrict__ dst, int n)
{
    for (int i = blockIdx.x * 256 + threadIdx.x; i < n; i += gridDim.x * 256) {
        float f = src[i];
        unsigned short hb = f2bf(f);
        unsigned short lb = f2bf(f - bf2f(hb));
        dst[i] = ((unsigned)hb << 16) | lb;
    }
}

// ---------------------------------------------------------------------------
// MFMA GEMM on packed split-bf16 (proven R6): layer-0 input transform only.
// ---------------------------------------------------------------------------
__global__ __launch_bounds__(256) void gemm_pk_mfma(
    const unsigned* __restrict__ A, const unsigned* __restrict__ W,
    const float* __restrict__ b0, const float* __restrict__ b1,
    float* __restrict__ C, int K, int N)
{
    __shared__ short Ahi[128][SP], Alo[128][SP], Whi[128][SP], Wlo[128][SP];

    const int tid  = threadIdx.x;
    const int lane = tid & 63;
    const int wv   = tid >> 6;
    const int wm   = (wv & 1) * 64;
    const int wn   = (wv >> 1) * 64;
    const int l15  = lane & 15;
    const int quad = lane >> 4;
    const int m0   = blockIdx.x * 128;
    const int n0   = blockIdx.y * 128;

    floatx4 acc[4][4];
    #pragma unroll
    for (int i = 0; i < 4; ++i)
        #pragma unroll
        for (int j = 0; j < 4; ++j)
            acc[i][j] = (floatx4){0.f, 0.f, 0.f, 0.f};

    for (int kc = 0; kc < K; kc += 32) {
        #pragma unroll
        for (int it = 0; it < 4; ++it) {
            const int lin = it * 256 + tid;
            const int row = lin >> 3;
            const int c4  = (lin & 7) * 4;
            uint4 va = *(const uint4*)&A[(size_t)(m0 + row) * K + kc + c4];
            uint2 ah, al;
            ah.x = (va.x >> 16) | (va.y & 0xffff0000u);
            ah.y = (va.z >> 16) | (va.w & 0xffff0000u);
            al.x = (va.x & 0xffffu) | (va.y << 16);
            al.y = (va.z & 0xffffu) | (va.w << 16);
            *(uint2*)&Ahi[row][c4] = ah;
            *(uint2*)&Alo[row][c4] = al;
            uint4 vw = *(const uint4*)&W[(size_t)(n0 + row) * K + kc + c4];
            uint2 wh, wl;
            wh.x = (vw.x >> 16) | (vw.y & 0xffff0000u);
            wh.y = (vw.z >> 16) | (vw.w & 0xffff0000u);
            wl.x = (vw.x & 0xffffu) | (vw.y << 16);
            wl.y = (vw.z & 0xffffu) | (vw.w << 16);
            *(uint2*)&Whi[row][c4] = wh;
            *(uint2*)&Wlo[row][c4] = wl;
        }
        __syncthreads();

        bf16x8 afh[4], afl[4], bfh[4], bfl[4];
        #pragma unroll
        for (int i = 0; i < 4; ++i) {
            afh[i] = *(const bf16x8*)&Ahi[wm + i * 16 + l15][quad * 8];
            afl[i] = *(const bf16x8*)&Alo[wm + i * 16 + l15][quad * 8];
            bfh[i] = *(const bf16x8*)&Whi[wn + i * 16 + l15][quad * 8];
            bfl[i] = *(const bf16x8*)&Wlo[wn + i * 16 + l15][quad * 8];
        }
        #pragma unroll
        for (int i = 0; i < 4; ++i)
            #pragma unroll
            for (int j = 0; j < 4; ++j) {
                acc[i][j] = __builtin_amdgcn_mfma_f32_16x16x32_bf16(afh[i], bfh[j], acc[i][j], 0, 0, 0);
                acc[i][j] = __builtin_amdgcn_mfma_f32_16x16x32_bf16(afh[i], bfl[j], acc[i][j], 0, 0, 0);
                acc[i][j] = __builtin_amdgcn_mfma_f32_16x16x32_bf16(afl[i], bfh[j], acc[i][j], 0, 0, 0);
            }
        __syncthreads();
    }

    #pragma unroll
    for (int i = 0; i < 4; ++i) {
        #pragma unroll
        for (int j = 0; j < 4; ++j) {
            const int n = n0 + wn + j * 16 + l15;
            const float bias = b0[n] + b1[n];
            #pragma unroll
            for (int r = 0; r < 4; ++r) {
                const int m = m0 + wm + i * 16 + quad * 4 + r;
                C[(size_t)m * N + n] = acc[i][j][r] + bias;
            }
        }
    }
}

// ---------------------------------------------------------------------------
// Stage 8 tagged h-cells into LDS hi/lo planes — ATOMIC (L2-bypassing) path.
// Used only as the retry fallback; returns nonzero on tag miss.
// ---------------------------------------------------------------------------
__device__ __forceinline__ unsigned stage8_atomic(
    const unsigned long long* __restrict__ src, int bb, int kk, unsigned exp,
    short (*Hs_hi)[HP2], short (*Hs_lo)[HP2])
{
    unsigned long long q0 = __hip_atomic_load(src + 0, __ATOMIC_RELAXED, __HIP_MEMORY_SCOPE_AGENT);
    unsigned long long q1 = __hip_atomic_load(src + 1, __ATOMIC_RELAXED, __HIP_MEMORY_SCOPE_AGENT);
    unsigned long long q2 = __hip_atomic_load(src + 2, __ATOMIC_RELAXED, __HIP_MEMORY_SCOPE_AGENT);
    unsigned long long q3 = __hip_atomic_load(src + 3, __ATOMIC_RELAXED, __HIP_MEMORY_SCOPE_AGENT);
    unsigned c0 = (unsigned)q0, c1 = (unsigned)(q0 >> 32);
    unsigned c2 = (unsigned)q1, c3 = (unsigned)(q1 >> 32);
    unsigned c4 = (unsigned)q2, c5 = (unsigned)(q2 >> 32);
    unsigned c6 = (unsigned)q3, c7 = (unsigned)(q3 >> 32);
    unsigned bad = ((c0 ^ exp) | (c1 ^ exp) | (c2 ^ exp) | (c3 ^ exp)
                  | (c4 ^ exp) | (c5 ^ exp) | (c6 ^ exp) | (c7 ^ exp)) & 0xFu;
    uint4 hiv, lov;
    hiv.x = (c0 >> 16) | (c1 & 0xffff0000u);
    hiv.y = (c2 >> 16) | (c3 & 0xffff0000u);
    hiv.z = (c4 >> 16) | (c5 & 0xffff0000u);
    hiv.w = (c6 >> 16) | (c7 & 0xffff0000u);
    lov.x = (c0 & 0xFFF0u) | ((c1 & 0xFFF0u) << 16);
    lov.y = (c2 & 0xFFF0u) | ((c3 & 0xFFF0u) << 16);
    lov.z = (c4 & 0xFFF0u) | ((c5 & 0xFFF0u) << 16);
    lov.w = (c6 & 0xFFF0u) | ((c7 & 0xFFF0u) << 16);
    *(uint4*)&Hs_hi[bb][kk] = hiv;
    *(uint4*)&Hs_lo[bb][kk] = lov;
    return bad;
}

// ---------------------------------------------------------------------------
// Stage 8 tagged h-cells — PLAIN CACHED path (fast). Only issued after the
// flag handshake; tag check retained, mismatch retries via stage8_atomic.
// ---------------------------------------------------------------------------
__device__ __forceinline__ unsigned stage8_plain(
    const unsigned* __restrict__ src, int bb, int kk, unsigned exp,
    short (*Hs_hi)[HP2], short (*Hs_lo)[HP2])
{
    const uint4 v0 = *(const uint4*)(src);
    const uint4 v1 = *(const uint4*)(src + 4);
    unsigned bad = ((v0.x ^ exp) | (v0.y ^ exp) | (v0.z ^ exp) | (v0.w ^ exp)
                  | (v1.x ^ exp) | (v1.y ^ exp) | (v1.z ^ exp) | (v1.w ^ exp)) & 0xFu;
    uint4 hiv, lov;
    hiv.x = (v0.x >> 16) | (v0.y & 0xffff0000u);
    hiv.y = (v0.z >> 16) | (v0.w & 0xffff0000u);
    hiv.z = (v1.x >> 16) | (v1.y & 0xffff0000u);
    hiv.w = (v1.z >> 16) | (v1.w & 0xffff0000u);
    lov.x = (v0.x & 0xFFF0u) | ((v0.y & 0xFFF0u) << 16);
    lov.y = (v0.z & 0xFFF0u) | ((v0.w & 0xFFF0u) << 16);
    lov.z = (v1.x & 0xFFF0u) | ((v1.y & 0xFFF0u) << 16);
    lov.w = (v1.z & 0xFFF0u) | ((v1.w & 0xFFF0u) << 16);
    *(uint4*)&Hs_hi[bb][kk] = hiv;
    *(uint4*)&Hs_lo[bb][kk] = lov;
    return bad;
}

// Tile stage over a generic (start, stride, count) index walk.
__device__ __forceinline__ void stage_tile_g(
    const unsigned* __restrict__ base, unsigned exp,
    int tstart, int pcount, int pstride,
    short (*Hs_hi)[HP2], short (*Hs_lo)[HP2])
{
    unsigned miss = 0;
    for (int p = 0; p < pcount; ++p) {
        const int idx = p * pstride + tstart;
        unsigned bad = stage8_plain(base + idx, idx >> 9, idx & 511,
                                    exp, Hs_hi, Hs_lo);
        miss |= (bad ? 1u : 0u) << p;
    }
    while (miss) {
        for (int p = 0; p < pcount; ++p) {
            if (miss & (1u << p)) {
                const int idx = p * pstride + tstart;
                if (!stage8_atomic((const unsigned long long*)(base + idx),
                                   idx >> 9, idx & 511, exp, Hs_hi, Hs_lo))
                    miss &= ~(1u << p);
            }
        }
    }
}

// Agent-scope relaxed poll (L2-bypassing). BOUNDED: the flag is a latency
// optimization only — the tag-retry staging path is a complete correctness
// protocol by itself, so falling through after the bound can never produce
// wrong results and converts any protocol stall into graceful degradation.
__device__ __forceinline__ void spin_flag(const unsigned* p) {
    int n = 0;
    while (__hip_atomic_load(p, __ATOMIC_RELAXED, __HIP_MEMORY_SCOPE_AGENT) == 0u) {
        if (++n > 65536) break;
    }
}

// ---------------------------------------------------------------------------
// FUSED two-layer persistent LSTM — WAVE-SPECIALIZED 512-thread blocks.
// Blocks 0..127 = layer 0; 128..255 = layer 1. WG (bt, jsl): batches
// [bt*32,+32) x 16 hidden units.
//
// Waves 0-3 (R-threads, tid<256): the serial recurrent pipeline — poll fR,
// stage Ra, R-MFMA (wave=gate), Gs_R, update, tagged h store, drain, flag.
// Waves 4-7 (X-threads): layer-1 only — poll fX, stage Xa, X-MFMA, Gs_X,
// CONCURRENTLY with the R chain on the other SIMDs. Update sums Gs_R+Gs_X.
// This removes the entire X phase (~1.3us + 2 barriers) from layer-1's
// serial period, making it symmetric with layer-0.
// Each thread holds ONE weight-frag array (its role's weights) -> VGPR flat.
// Layer-0's X-waves help stage Ra (512-thread split).
// Sync protocol unchanged from R2/R3 (proven): tagged relaxed-agent h
// stores, barrier drain, relaxed-agent flag; consumers flag-gate then
// stage with plain cached loads; tags catch residual staleness (0xA
// harness poison never matches).
// ---------------------------------------------------------------------------
__global__ __launch_bounds__(512, 2) void lstm_fused(
    const float* __restrict__ xg,     // [T][B][4H] layer-0 (biases included)
    const float* __restrict__ w_hh0,  // [4H][H] fp32
    const float* __restrict__ w_ih1,  // [4H][H] fp32
    const float* __restrict__ w_hh1,  // [4H][H] fp32
    const float* __restrict__ b_ih1, const float* __restrict__ b_hh1,
    unsigned* __restrict__ hpack0,    // [T+1][B][H] tagged, block 0 zeroed
    unsigned* __restrict__ hpack1,    // [T+1][B][H] tagged, block 0 zeroed
    unsigned* __restrict__ flags)     // [2][T+1][4][32] step flags (zeroed)
{
    __shared__ short Ra_hi[32][HP2], Ra_lo[32][HP2];   // recurrent h tile
    __shared__ short Xa_hi[32][HP2], Xa_lo[32][HP2];   // layer-1 input h0 tile
    __shared__ float GsR[64][33];
    __shared__ float GsX[64][33];

    const int tid  = threadIdx.x;          // 0..511
    const int lane = tid & 63;
    const int wv   = tid >> 6;             // 0..7
    const bool isR = wv < 4;               // R-pipeline waves
    const int gate = wv & 3;               // gate for MFMA (both roles)
    const bool isB = blockIdx.x >= 128;
    const int blk  = blockIdx.x & 127;
    const int bt   = blk & 3;
    const int jsl  = blk >> 2;             // producer j-slice id 0..31
    const int j0   = jsl * 16;             // 16-unit slice
    const int l15  = lane & 15;
    const int quad = lane >> 4;
    const int tid_x = tid - 256;           // X-thread linear id (valid if !isR)

    // ---- preload weight frags: ONE array per thread, role-dependent ----
    // R-threads: recurrent weights (w_hh0/w_hh1). X-threads (layer-1): w_ih1.
    bf16x8 wf_hi[16], wf_lo[16];
    {
        const float* wsrc = isR ? (isB ? w_hh1 : w_hh0) : w_ih1;
        if (isR || isB) {
            const float* wrow = wsrc + (size_t)(gate * HH + j0 + l15) * HH + quad * 8;
            #pragma unroll
            for (int kc = 0; kc < 16; ++kc) {
                float f[8];
                *(float4*)&f[0] = *(const float4*)&wrow[kc * 32];
                *(float4*)&f[4] = *(const float4*)&wrow[kc * 32 + 4];
                bf16x8 vh, vl;
                #pragma unroll
                for (int j = 0; j < 8; ++j) {
                    unsigned short hb = f2bf(f[j]);
                    vh[j] = (short)hb;
                    vl[j] = (short)f2bf(f[j] - bf2f(hb));
                }
                wf_hi[kc] = vh; wf_lo[kc] = vl;
            }
        }
    }

    // update-phase roles (R-threads only): cells (j_u, bu) and (j_u, bu+16)
    const int j_u = tid & 15;
    const int bu  = (tid >> 4) & 15;
    float bias_i = 0.f, bias_f = 0.f, bias_g = 0.f, bias_o = 0.f;
    if (isB && isR) {
        bias_i = b_ih1[j0 + j_u]            + b_hh1[j0 + j_u];
        bias_f = b_ih1[HH + j0 + j_u]       + b_hh1[HH + j0 + j_u];
        bias_g = b_ih1[2 * HH + j0 + j_u]   + b_hh1[2 * HH + j0 + j_u];
        bias_o = b_ih1[3 * HH + j0 + j_u]   + b_hh1[3 * HH + j0 + j_u];
    }

    // zero GsX once (layer-0 never writes it; update always reads it)
    for (int i = tid; i < 64 * 33; i += 512)
        ((float*)GsX)[i] = 0.f;
    __syncthreads();

    unsigned* hp_rec = isB ? hpack1 : hpack0;
    const int layerBase = isB ? 65 : 0;
    float c0 = 0.f, c1 = 0.f;

    for (int t = 0; t < TT; ++t) {
        const unsigned* rec_base = hp_rec + (size_t)t * (BB * HH) + (size_t)bt * 32 * HH;
        const unsigned* inp_base = hpack0 + (size_t)(t + 1) * (BB * HH) + (size_t)bt * 32 * HH;
        const unsigned expR = (unsigned)t % 9u;
        const unsigned expX = (unsigned)(t + 1) % 9u;
        const unsigned* fR = flags + ((layerBase + t) * 4 + bt) * 32;
        const unsigned* fX = flags + ((t + 1) * 4 + bt) * 32;

        // layer-0 R-threads: xg prefetch (overlaps poll + staging latency)
        float xgv[2][4];
        if (!isB && isR) {
            #pragma unroll
            for (int ccell = 0; ccell < 2; ++ccell) {
                const int b = bu + ccell * 16;
                const float* base = xg + (size_t)t * (BB * GG)
                                  + (size_t)(bt * 32 + b) * GG + j0 + j_u;
                xgv[ccell][0] = base[0];
                xgv[ccell][1] = base[HH];
                xgv[ccell][2] = base[2 * HH];
                xgv[ccell][3] = base[3 * HH];
            }
        }

        // ---- phase A: polls (wave 0 -> fR, wave 4 -> fX) ----
        if (wv == 0 && lane < 32 && t > 0 && lane != jsl) spin_flag(fR + lane);
        if (isB && wv == 4 && lane < 32) spin_flag(fX + lane);
        __syncthreads();                                   // B1

        // ---- phase B: staging ----
        if (isB) {
            if (isR) stage_tile_g(rec_base, expR, tid * 8,   8, 2048, Ra_hi, Ra_lo);
            else     stage_tile_g(inp_base, expX, tid_x * 8, 8, 2048, Xa_hi, Xa_lo);
        } else {
            stage_tile_g(rec_base, expR, tid * 8, 4, 4096, Ra_hi, Ra_lo);
        }
        __syncthreads();                                   // B2

        // ---- phase C: MFMA + Gs writes ----
        if (isR) {
            floatx4 a0 = {0.f,0.f,0.f,0.f}, a1 = {0.f,0.f,0.f,0.f};
            #pragma unroll
            for (int kc = 0; kc < 16; ++kc) {
                const int off = kc * 32 + quad * 8;
                bf16x8 r0h = *(const bf16x8*)&Ra_hi[l15][off];
                bf16x8 r0l = *(const bf16x8*)&Ra_lo[l15][off];
                bf16x8 r1h = *(const bf16x8*)&Ra_hi[16 + l15][off];
                bf16x8 r1l = *(const bf16x8*)&Ra_lo[16 + l15][off];
                a0 = __builtin_amdgcn_mfma_f32_16x16x32_bf16(wf_hi[kc], r0h, a0, 0, 0, 0);
                a1 = __builtin_amdgcn_mfma_f32_16x16x32_bf16(wf_hi[kc], r1h, a1, 0, 0, 0);
                a0 = __builtin_amdgcn_mfma_f32_16x16x32_bf16(wf_hi[kc], r0l, a0, 0, 0, 0);
                a1 = __builtin_amdgcn_mfma_f32_16x16x32_bf16(wf_hi[kc], r1l, a1, 0, 0, 0);
                a0 = __builtin_amdgcn_mfma_f32_16x16x32_bf16(wf_lo[kc], r0h, a0, 0, 0, 0);
                a1 = __builtin_amdgcn_mfma_f32_16x16x32_bf16(wf_lo[kc], r1h, a1, 0, 0, 0);
            }
            #pragma unroll
            for (int r = 0; r < 4; ++r) {
                GsR[gate * 16 + quad * 4 + r][l15]      = a0[r];
                GsR[gate * 16 + quad * 4 + r][16 + l15] = a1[r];
            }
        } else if (isB) {
            floatx4 a0 = {0.f,0.f,0.f,0.f}, a1 = {0.f,0.f,0.f,0.f};
            #pragma unroll
            for (int kc = 0; kc < 16; ++kc) {
                const int off = kc * 32 + quad * 8;
                bf16x8 x0h = *(const bf16x8*)&Xa_hi[l15][off];
                bf16x8 x0l = *(const bf16x8*)&Xa_lo[l15][off];
                bf16x8 x1h = *(const bf16x8*)&Xa_hi[16 + l15][off];
                bf16x8 x1l = *(const bf16x8*)&Xa_lo[16 + l15][off];
                a0 = __builtin_amdgcn_mfma_f32_16x16x32_bf16(wf_hi[kc], x0h, a0, 0, 0, 0);
                a1 = __builtin_amdgcn_mfma_f32_16x16x32_bf16(wf_hi[kc], x1h, a1, 0, 0, 0);
                a0 = __builtin_amdgcn_mfma_f32_16x16x32_bf16(wf_hi[kc], x0l, a0, 0, 0, 0);
                a1 = __builtin_amdgcn_mfma_f32_16x16x32_bf16(wf_hi[kc], x1l, a1, 0, 0, 0);
                a0 = __builtin_amdgcn_mfma_f32_16x16x32_bf16(wf_lo[kc], x0h, a0, 0, 0, 0);
                a1 = __builtin_amdgcn_mfma_f32_16x16x32_bf16(wf_lo[kc], x1h, a1, 0, 0, 0);
            }
            #pragma unroll
            for (int r = 0; r < 4; ++r) {
                GsX[gate * 16 + quad * 4 + r][l15]      = a0[r];
                GsX[gate * 16 + quad * 4 + r][16 + l15] = a1[r];
            }
        }
        __syncthreads();                                   // B3

        // ---- phase D: elementwise update (R-threads); tagged h store ----
        if (isR) {
            const unsigned tag = (unsigned)(t + 1) % 9u;
            #pragma unroll
            for (int ccell = 0; ccell < 2; ++ccell) {
                const int b = bu + ccell * 16;
                float gi = GsR[j_u][b]      + GsX[j_u][b];
                float gf = GsR[16 + j_u][b] + GsX[16 + j_u][b];
                float gg = GsR[32 + j_u][b] + GsX[32 + j_u][b];
                float go = GsR[48 + j_u][b] + GsX[48 + j_u][b];
                if (isB) { gi += bias_i; gf += bias_f; gg += bias_g; go += bias_o; }
                else     { gi += xgv[ccell][0]; gf += xgv[ccell][1];
                           gg += xgv[ccell][2]; go += xgv[ccell][3]; }
                const float si = 1.f / (1.f + __expf(-gi));
                const float sf = 1.f / (1.f + __expf(-gf));
                const float tg = 2.f / (1.f + __expf(-2.f * gg)) - 1.f;
                const float so = 1.f / (1.f + __expf(-go));
                float& cr = ccell ? c1 : c0;
                cr = sf * cr + si * tg;
                const float th = 2.f / (1.f + __expf(-2.f * cr)) - 1.f;
                const float hval = so * th;
                const unsigned short hb = f2bf(hval);
                const unsigned short lb = f2bf(hval - bf2f(hb));
                const unsigned pk = ((unsigned)hb << 16) | ((unsigned)lb & 0xFFF0u) | tag;
                __hip_atomic_store(
                    &hp_rec[(size_t)(t + 1) * (BB * HH) + (size_t)(bt * 32 + b) * HH + j0 + j_u],
                    pk, __ATOMIC_RELAXED, __HIP_MEMORY_SCOPE_AGENT);
            }
        }
        __syncthreads();                                   // B4 (drains stores)

        // ---- publish: flag store for this slice (after the drain) ----
        if (tid == 0)
            __hip_atomic_store(
                flags + ((layerBase + (t + 1)) * 4 + bt) * 32 + jsl,
                1u, __ATOMIC_RELAXED, __HIP_MEMORY_SCOPE_AGENT);
    }
}

// ---------------------------------------------------------------------------
// Classifier split-K partial GEMM on tagged h cells (mask tag nibble)
// ---------------------------------------------------------------------------
__global__ __launch_bounds__(256) void cls_partial_kernel(
    const unsigned* __restrict__ A, const float* __restrict__ W,
    float* __restrict__ part)
{
    const int n0 = blockIdx.x * 64;
    const int s  = blockIdx.y;
    const int kbase = s * 2048;
    const int tid = threadIdx.x;
    __shared__ float As[32][68];
    __shared__ float Bs[32][68];
    const int tm = tid >> 4, tn = tid & 15;
    float acc[4][4] = {};

    for (int kt = 0; kt < 2048; kt += 32) {
        #pragma unroll
        for (int q = tid; q < 512; q += 256) {
            const int mm = q >> 3;
            const int kq = q & 7;
            uint4 v = *(const uint4*)&A[(size_t)mm * KFLAT + kbase + kt + kq * 4];
            As[kq*4+0][mm] = pk2f(v.x & 0xFFFFFFF0u); As[kq*4+1][mm] = pk2f(v.y & 0xFFFFFFF0u);
            As[kq*4+2][mm] = pk2f(v.z & 0xFFFFFFF0u); As[kq*4+3][mm] = pk2f(v.w & 0xFFFFFFF0u);
            float4 w = *(const float4*)&W[(size_t)(n0 + mm) * KFLAT + kbase + kt + kq * 4];
            Bs[kq*4+0][mm] = w.x; Bs[kq*4+1][mm] = w.y;
            Bs[kq*4+2][mm] = w.z; Bs[kq*4+3][mm] = w.w;
        }
        __syncthreads();
        #pragma unroll
        for (int k = 0; k < 32; ++k) {
            float4 a = *(const float4*)&As[k][tm * 4];
            float4 b = *(const float4*)&Bs[k][tn * 4];
            acc[0][0] += a.x*b.x; acc[0][1] += a.x*b.y; acc[0][2] += a.x*b.z; acc[0][3] += a.x*b.w;
            acc[1][0] += a.y*b.x; acc[1][1] += a.y*b.y; acc[1][2] += a.y*b.z; acc[1][3] += a.y*b.w;
            acc[2][0] += a.z*b.x; acc[2][1] += a.z*b.y; acc[2][2] += a.z*b.z; acc[2][3] += a.z*b.w;
            acc[3][0] += a.w*b.x; acc[3][1] += a.w*b.y; acc[3][2] += a.w*b.z; acc[3][3] += a.w*b.w;
        }
        __syncthreads();
    }
    #pragma unroll
    for (int i = 0; i < 4; ++i) {
        const int m = tm * 4 + i;
        #pragma unroll
        for (int j = 0; j < 4; ++j) {
            part[((size_t)s * 64 + m) * 512 + n0 + tn * 4 + j] = acc[i][j];
        }
    }
}

// ---------------------------------------------------------------------------
// Classifier finish (unchanged)
// ---------------------------------------------------------------------------
__global__ __launch_bounds__(256) void cls_final_kernel(
    const float* __restrict__ part, const float* __restrict__ b1,
    const float* __restrict__ w2, const float* __restrict__ b2,
    float* __restrict__ out)
{
    const int t = blockIdx.x;
    __shared__ float hm[512];
    for (int n = threadIdx.x; n < 512; n += 256) {
        float sacc = b1[n];
        for (int sl = 0; sl < 32; ++sl)
            sacc += part[((size_t)sl * 64 + t) * 512 + n];
        hm[n] = fmaxf(sacc, 0.f);
    }
    __syncthreads();
    if (threadIdx.x < NCC) {
        float sacc = b2[threadIdx.x];
        const float* wr = w2 + (size_t)threadIdx.x * 512;
        for (int n = 0; n < 512; ++n) sacc += hm[n] * wr[n];
        out[t * NCC + threadIdx.x] = sacc;
    }
}

// ---------------------------------------------------------------------------
extern "C" void kernel_launch(void* const* d_in, const int* in_sizes, int n_in,
                              void* d_out, int out_size, void* d_ws, size_t ws_size,
                              hipStream_t stream)
{
    const float* x     = (const float*)d_in[0];
    const float* w_ih0 = (const float*)d_in[1];
    const float* w_hh0 = (const float*)d_in[2];
    const float* b_ih0 = (const float*)d_in[3];
    const float* b_hh0 = (const float*)d_in[4];
    const float* w_ih1 = (const float*)d_in[5];
    const float* w_hh1 = (const float*)d_in[6];
    const float* b_ih1 = (const float*)d_in[7];
    const float* b_hh1 = (const float*)d_in[8];
    const float* w1    = (const float*)d_in[9];
    const float* b1    = (const float*)d_in[10];
    const float* w2    = (const float*)d_in[11];
    const float* b2    = (const float*)d_in[12];
    float* out = (float*)d_out;

    // Workspace (~102.1 MB): hpack1 region is ALIASED over xpk/w0pk (dead
    // after the layer-0 GEMM). All t>=1 h reads are flag-gated (flags
    // zeroed each launch) and tag-checked, so no 0xFF scrub is needed.
    // flags alias the part region (part written only after lstm_fused).
    float*    ws     = (float*)d_ws;
    float*    xg     = ws;                                      // 64 MB
    unsigned* hpack0 = (unsigned*)(xg + (size_t)8192 * 2048);   // 17.04 MB
    unsigned* hpack1 = hpack0 + (size_t)65 * BB * HH;           // 17.04 MB (aliased)
    unsigned* xpk    = hpack1;                                  // 8 MB   (dies at GEMM)
    unsigned* w0pk   = xpk + (size_t)8192 * IND;                // 2 MB   (dies at GEMM)
    float*    part   = (float*)(hpack1 + (size_t)65 * BB * HH); // 4 MB
    unsigned* flags  = (unsigned*)part;                         // 66.6 KB (dies at cls)

    // ---- pack layer-0 GEMM inputs ----
    pack_split_kernel<<<1024, 256, 0, stream>>>(x, xpk, 8192 * IND);
    pack_split_kernel<<<512,  256, 0, stream>>>(w_ih0, w0pk, GG * IND);
    hipMemsetAsync(hpack0, 0, (size_t)BB * HH * sizeof(unsigned), stream);  // h0 t=0
    hipMemsetAsync(flags, 0, (size_t)2 * 65 * 4 * 32 * sizeof(unsigned), stream);

    // ---- layer-0 input transform ----
    gemm_pk_mfma<<<dim3(8192 / 128, GG / 128), 256, 0, stream>>>(
        xpk, w0pk, b_ih0, b_hh0, xg, IND, GG);

    // ---- zero t=0 block of hpack1 (after GEMM: aliased region now dead) ----
    hipMemsetAsync(hpack1, 0, (size_t)BB * HH * sizeof(unsigned), stream);

    // ---- fused two-layer recurrence (512-thread wave-specialized blocks) ----
    lstm_fused<<<256, 512, 0, stream>>>(
        xg, w_hh0, w_ih1, w_hh1, b_ih1, b_hh1, hpack0, hpack1, flags);

    // ---- classifier (tagged h1, blocks 1..64) ----
    cls_partial_kernel<<<dim3(512 / 64, 32), 256, 0, stream>>>(
        hpack1 + (size_t)BB * HH, w1, part);
    cls_final_kernel<<<64, 256, 0, stream>>>(part, b1, w2, b2, out);
}